// Round 11
// baseline (246.074 us; speedup 1.0000x reference)
//
#include <hip/hip_runtime.h>
#include <math.h>

#define NB 2048
typedef float f32x4 __attribute__((ext_vector_type(4)));
typedef float f32x2 __attribute__((ext_vector_type(2)));

// pre[] float offsets (folded weights)
#define P_WAL 0
#define P_WBL 1024
#define P_WLBL 2048
#define P_WNAL 3072
#define P_WEFF 4096
#define P_BWA 4160
#define P_BWB 4176
#define P_BWL 4192
#define P_BWN 4208
#define P_C0  4224

// ws float offsets
#define WS_BNPART 4352
#define WS_COEF   135424
#define WS_FEAT16 140000

__device__ __forceinline__ unsigned short f2bf(float f) {
  unsigned int u = __float_as_uint(f);
  u += 0x7fffu + ((u >> 16) & 1u);
  return (unsigned short)(u >> 16);
}
__device__ __forceinline__ unsigned int pack2bf(float lo, float hi) {
  return (unsigned int)f2bf(lo) | ((unsigned int)f2bf(hi) << 16);
}
__device__ __forceinline__ float bflo(unsigned int u) { return __uint_as_float(u << 16); }
__device__ __forceinline__ float bfhi(unsigned int u) { return __uint_as_float(u & 0xffff0000u); }

#define BSTAGE(MASK, HALF)                                        \
  { const bool hi_ = (lane & (MASK)) != 0;                        \
    _Pragma("unroll")                                             \
    for (int k_ = 0; k_ < (HALF); ++k_) {                         \
      float mine_ = hi_ ? a[k_ + (HALF)] : a[k_];                 \
      float oth_  = hi_ ? a[k_] : a[k_ + (HALF)];                 \
      a[k_] = mine_ + __shfl_xor(oth_, (MASK));                   \
    } }

// ---------------------------------------------------------------- k0: fold weights
__global__ __launch_bounds__(256) void k0_pre(const float* __restrict__ W_lin,
                                              const float* __restrict__ b_lin,
                                              const float* __restrict__ W_att,
                                              const float* __restrict__ Wa,
                                              const float* __restrict__ Wb,
                                              const float* __restrict__ Wn,
                                              const float* __restrict__ Wl,
                                              float* __restrict__ pre) {
  int t = threadIdx.x;
  for (int i = t; i < 1024; i += 256) {
    int o = i >> 6, d = i & 63;
    float sa = 0.f, sb = 0.f;
    for (int c = 0; c < 32; ++c) {
      float wl = W_lin[c * 64 + d];
      sa += Wa[o * 32 + c] * wl;
      sb += Wb[o * 32 + c] * wl;
    }
    pre[P_WAL + i] = sa;
    pre[P_WBL + i] = sb;
  }
  if (t < 64) {
    float s = 0.f;
    for (int c = 0; c < 32; ++c) s += W_att[c] * W_lin[c * 64 + t];
    pre[P_WEFF + t] = s;
  }
  if (t < 16) {
    float sa = 0.f, sb = 0.f;
    for (int c = 0; c < 32; ++c) {
      sa += Wa[t * 32 + c] * b_lin[c];
      sb += Wb[t * 32 + c] * b_lin[c];
    }
    pre[P_BWA + t] = sa;
    pre[P_BWB + t] = sb;
  }
  if (t == 0) {
    float s = 0.f;
    for (int c = 0; c < 32; ++c) s += W_att[c] * b_lin[c];
    pre[P_C0] = s;
  }
  __syncthreads();
  for (int i = t; i < 1024; i += 256) {
    int p_ = i >> 6, d = i & 63;
    float sl = 0.f, sn = 0.f;
    for (int o = 0; o < 16; ++o) {
      sl += Wl[p_ * 16 + o] * pre[P_WBL + o * 64 + d];
      sn += Wn[p_ * 16 + o] * pre[P_WAL + o * 64 + d];
    }
    pre[P_WLBL + i] = sl;
    pre[P_WNAL + i] = sn;
  }
  if (t < 16) {
    float sl = 0.f, sn = 0.f;
    for (int o = 0; o < 16; ++o) {
      sl += Wl[t * 16 + o] * pre[P_BWB + o];
      sn += Wn[t * 16 + o] * pre[P_BWA + o];
    }
    pre[P_BWL + t] = sl;
    pre[P_BWN + t] = sn;
  }
}

// ---------------------------------------------------------------- k1: merged per-batch module, 1024 threads, 32 waves/CU
__global__ __launch_bounds__(1024, 2) void k1_merged(
    const float* __restrict__ xl_all, const float* __restrict__ xg_all,
    const float* __restrict__ pre, const float* __restrict__ Wc_g,
    const float* __restrict__ Wd_g, unsigned int* __restrict__ feat16,
    float* __restrict__ bn_part) {
  __shared__ __align__(16) float xaggi[128 * 68];     // 34816 B
  __shared__ __align__(16) float RU[5120];            // 20480 B: scratch5 [5][16][64] ; later slabI/V [128][20] x2
  __shared__ __align__(16) float xlogL[128 * 20];     // 10240 B (pitch 20: 16B-aligned rows)
  __shared__ float s_Wd[32][33];                      // 4224 B
  __shared__ float pe[80];
  __shared__ float xagg_inter[320];
  __shared__ float s_small[160];
  __shared__ float part1[16][33];                     // 2112 B
  __shared__ float part2[16][33];

  float* slabI = RU;                  // [128][20], cols 0..15 used
  float* slabV = RU + 2560;           // [128][20]

  const int t = threadIdx.x;
  const int b = blockIdx.x;
  const int lane = t & 63;
  const int w = t >> 6;               // 16 waves
  const int q = lane >> 4;
  const int i16 = lane & 15;
  const int n2 = t >> 3;              // phase 3/4: n index (0..127)
  const int q3 = t & 7;               // phase 3/4: 8-way split per n

  const float* xl = xl_all + (size_t)b * (5 * 128 * 64);
  const f32x4 weff4 = ((const f32x4*)(pre + P_WEFF))[i16];
  const float c0 = pre[P_C0];

  // stage Wd -> LDS (read in phase 4)
  if (t < 1024) { int i = t; if (i < 1024) s_Wd[i >> 5][i & 31] = Wd_g[i]; }

  // ---------------- phase 1: streaming softmax aggregation (2 rows/thread)
  const float* xb = xl + (size_t)(8 * w + q) * 64 + 4 * i16;
  f32x4 xA[2], xB[2], acc[2];
  float Zk[2];
  #pragma unroll
  for (int k = 0; k < 2; ++k) {
    acc[k] = (f32x4)0.f;
    Zk[k] = 0.f;
    xA[k] = *(const f32x4*)(xb + k * 256);
  }
  #pragma unroll
  for (int m = 0; m < 5; ++m) {
    f32x4* xc = (m & 1) ? xB : xA;
    f32x4* xn = (m & 1) ? xA : xB;
    if (m < 4) {
      const float* np = xb + (size_t)(m + 1) * 8192;
      #pragma unroll
      for (int k = 0; k < 2; ++k) xn[k] = *(const f32x4*)(np + k * 256);
    }
    float a0, a1;
    {
      f32x4 p0 = xc[0] * weff4, p1 = xc[1] * weff4;
      a0 = p0.x + p0.y + p0.z + p0.w;
      a1 = p1.x + p1.y + p1.z + p1.w;
    }
    #pragma unroll
    for (int mask = 1; mask <= 8; mask <<= 1) {
      a0 += __shfl_xor(a0, mask);
      a1 += __shfl_xor(a1, mask);
    }
    float e0 = __expf(a0 + c0), e1 = __expf(a1 + c0);
    Zk[0] += e0; Zk[1] += e1;
    f32x4 pim;
    {
      f32x4 pr0 = e0 * xc[0];
      f32x4 pr1 = e1 * xc[1];
      acc[0] += pr0; acc[1] += pr1;
      pim = pr0 + pr1;
    }
    float se = e0 + e1;
    #pragma unroll
    for (int mask = 16; mask <= 32; mask <<= 1) {
      pim.x += __shfl_xor(pim.x, mask);
      pim.y += __shfl_xor(pim.y, mask);
      pim.z += __shfl_xor(pim.z, mask);
      pim.w += __shfl_xor(pim.w, mask);
      se += __shfl_xor(se, mask);
    }
    if (lane < 16) {
      ((f32x4*)RU)[(m * 16 + w) * 16 + i16] = pim;
      if (i16 == 0) pe[m * 16 + w] = se;
    }
  }
  #pragma unroll
  for (int k = 0; k < 2; ++k) {
    float invz = 1.f / Zk[k];
    f32x4 v = acc[k] * invz;
    int r = 8 * w + 4 * k + q;
    *(f32x4*)&xaggi[r * 68 + 4 * i16] = v;
  }
  __syncthreads();  // bar1

  // ---------------- seg A: inter-combine (reads RU-as-scratch5) + xlog -> LDS
  if (t < 320) {
    int mm = t >> 6, d = t & 63;
    const float* sp = RU + mm * 1024;
    float s = 0.f;
    #pragma unroll
    for (int j = 0; j < 16; ++j) s += sp[j * 64 + d];
    float sume = 0.f;
    #pragma unroll
    for (int j = 0; j < 16; ++j) sume += pe[mm * 16 + j];
    xagg_inter[mm * 64 + d] = s / sume;
  } else if (t >= 896) {
    int n = t - 896;
    const f32x4* xgr = (const f32x4*)(xg_all + ((size_t)b * 128 + n) * 32);
    f32x4 xv[8];
    #pragma unroll
    for (int j = 0; j < 8; ++j) xv[j] = xgr[j];
    #pragma unroll
    for (int o = 0; o < 16; ++o) {
      f32x4 s = (f32x4)0.f;
      #pragma unroll
      for (int j = 0; j < 8; ++j) s += xv[j] * *(const f32x4*)(Wc_g + o * 32 + 4 * j);
      xlogL[n * 20 + o] = s.x + s.y + s.z + s.w;
    }
  }
  __syncthreads();  // bar2 (scratch5 dead -> slabs may overwrite RU)

  // ---------------- seg B: per-s projections into slabs + s_small
  if (t < 512) {
    const int q2 = __builtin_amdgcn_readfirstlane(t >> 7);   // 0..3 wave-uniform
    const int s2 = t & 127;
    const float* Wbase = pre + ((q2 < 2) ? P_WBL : P_WLBL) + (q2 & 1) * 512;
    const float* xrow = &xaggi[s2 * 68];
    float acc2[8];
    #pragma unroll
    for (int r = 0; r < 8; ++r) acc2[r] = 0.f;
    #pragma unroll
    for (int c = 0; c < 64; c += 4) {
      f32x4 xa = *(const f32x4*)(xrow + c);
      #pragma unroll
      for (int r = 0; r < 8; ++r)
        acc2[r] += xa.x * Wbase[r * 64 + c] + xa.y * Wbase[r * 64 + c + 1] +
                   xa.z * Wbase[r * 64 + c + 2] + xa.w * Wbase[r * 64 + c + 3];
    }
    const int bb = ((q2 < 2) ? P_BWB : P_BWL) + (q2 & 1) * 8;
    float* dst = ((q2 < 2) ? slabI : slabV) + s2 * 20 + (q2 & 1) * 8;
    f32x4 o0, o1;
    o0.x = acc2[0] + pre[bb + 0];
    o0.y = acc2[1] + pre[bb + 1];
    o0.z = acc2[2] + pre[bb + 2];
    o0.w = acc2[3] + pre[bb + 3];
    o1.x = acc2[4] + pre[bb + 4];
    o1.y = acc2[5] + pre[bb + 5];
    o1.z = acc2[6] + pre[bb + 6];
    o1.w = acc2[7] + pre[bb + 7];
    *(f32x4*)dst = o0;
    *(f32x4*)(dst + 4) = o1;
  } else if (t < 672) {
    int tt = t - 512;
    int o2 = tt & 31, mm = tt >> 5;
    const float* wr = pre + ((o2 < 16) ? (P_WAL + o2 * 64) : (P_WNAL + (o2 - 16) * 64));
    float p = 0.f;
    #pragma unroll
    for (int d = 0; d < 64; ++d) p += wr[d] * xagg_inter[mm * 64 + d];
    p += (o2 < 16) ? pre[P_BWA + o2] : pre[P_BWN + (o2 - 16)];
    if (o2 < 16) s_small[mm * 16 + o2] = p;
    else s_small[80 + mm * 16 + (o2 - 16)] = p;
  }
  __syncthreads();  // bar3

  // ---------------- phase 3: f_intra partial sums, i = q3 + 8k (conflict-free pitch 20)
  f32x4 xlg[4];
  #pragma unroll
  for (int c = 0; c < 4; ++c) xlg[c] = *(const f32x4*)&xlogL[n2 * 20 + 4 * c];
  float sum = 0.f;
  f32x4 fav[4];
  #pragma unroll
  for (int c = 0; c < 4; ++c) fav[c] = (f32x4)0.f;
  #pragma unroll 4
  for (int k = 0; k < 16; ++k) {
    const int i = q3 + 8 * k;
    const f32x4* rI = (const f32x4*)&slabI[i * 20];
    f32x4 d4 = xlg[0] * rI[0] + xlg[1] * rI[1] + xlg[2] * rI[2] + xlg[3] * rI[3];
    float e = __expf(d4.x + d4.y + d4.z + d4.w);
    sum += e;
    const f32x4* rV = (const f32x4*)&slabV[i * 20];
    #pragma unroll
    for (int c = 0; c < 4; ++c) fav[c] += e * rV[c];
  }
  // full-replication combine over the 8 q3-partners (lane bits 0..2)
  #pragma unroll
  for (int mask = 1; mask <= 4; mask <<= 1) {
    sum += __shfl_xor(sum, mask);
    #pragma unroll
    for (int c = 0; c < 4; ++c) {
      fav[c].x += __shfl_xor(fav[c].x, mask);
      fav[c].y += __shfl_xor(fav[c].y, mask);
      fav[c].z += __shfl_xor(fav[c].z, mask);
      fav[c].w += __shfl_xor(fav[c].w, mask);
    }
  }
  const float inv = 1.f / sum;
  f32x4 fin[4];
  #pragma unroll
  for (int c = 0; c < 4; ++c) fin[c] = fav[c] * inv;

  // ---------------- phase 4: f_inter, feat (4 outputs/thread), BN partials
  float L[5], mx3 = -1e30f;
  #pragma unroll
  for (int mm = 0; mm < 5; ++mm) {
    float p = 0.f;
    #pragma unroll
    for (int c = 0; c < 4; ++c) {
      #pragma unroll
      for (int jj = 0; jj < 4; ++jj) p += xlg[c][jj] * s_small[mm * 16 + 4 * c + jj];
    }
    L[mm] = p;
    mx3 = fmaxf(mx3, p);
  }
  float sum3 = 0.f;
  #pragma unroll
  for (int mm = 0; mm < 5; ++mm) { L[mm] = __expf(L[mm] - mx3); sum3 += L[mm]; }
  const float inv3 = 1.f / sum3;
  f32x4 fi[4];
  #pragma unroll
  for (int c = 0; c < 4; ++c) {
    f32x4 r;
    #pragma unroll
    for (int jj = 0; jj < 4; ++jj) {
      float p = 0.f;
      #pragma unroll
      for (int mm = 0; mm < 5; ++mm) p += L[mm] * s_small[80 + mm * 16 + 4 * c + jj];
      r[jj] = p * inv3;
    }
    fi[c] = r;
  }
  float fo[4];
  #pragma unroll
  for (int j = 0; j < 4; ++j) {
    const int o = 4 * q3 + j;
    float p = 0.f;
    #pragma unroll
    for (int c = 0; c < 4; ++c) {
      #pragma unroll
      for (int jj = 0; jj < 4; ++jj) {
        p += fi[c][jj] * s_Wd[o][4 * c + jj];
        p += fin[c][jj] * s_Wd[o][16 + 4 * c + jj];
      }
    }
    fo[j] = p;
  }
  {
    uint2 u;
    u.x = pack2bf(fo[0], fo[1]);
    u.y = pack2bf(fo[2], fo[3]);
    ((uint2*)feat16)[(size_t)b * 1024 + n2 * 8 + q3] = u;
  }
  // BN partials: reduce over 8 n-partners (lane bits 3,4 via butterfly; bit 5 via shfl32)
  const int omap = 4 * q3 + 2 * ((lane >> 3) & 1) + ((lane >> 4) & 1);
  {
    float a[4];
    #pragma unroll
    for (int j = 0; j < 4; ++j) a[j] = fo[j];
    BSTAGE(8, 2) BSTAGE(16, 1)
    a[0] += __shfl_xor(a[0], 32);
    if (lane < 32) part1[w][omap] = a[0];
  }
  {
    float a[4];
    #pragma unroll
    for (int j = 0; j < 4; ++j) a[j] = fo[j] * fo[j];
    BSTAGE(8, 2) BSTAGE(16, 1)
    a[0] += __shfl_xor(a[0], 32);
    if (lane < 32) part2[w][omap] = a[0];
  }
  __syncthreads();  // bar4
  if (t < 64) {
    int c = t & 31, h = t >> 5;
    float v = 0.f;
    #pragma unroll
    for (int j = 0; j < 16; ++j) v += h ? part2[j][c] : part1[j][c];
    bn_part[(size_t)b * 64 + h * 32 + c] = v;
  }
}

// ---------------------------------------------------------------- k2: BN coefficients (one block per channel)
__global__ __launch_bounds__(256, 1) void k2_stats(const float* __restrict__ bn_part,
                                                   const float* __restrict__ gamma,
                                                   const float* __restrict__ beta,
                                                   float* __restrict__ coef) {
  __shared__ float red[2][4];
  const int c = blockIdx.x;              // 0..31
  const int t = threadIdx.x;
  const int lane = t & 63, w = t >> 6;
  float s1 = 0.f, s2 = 0.f;
  for (int bb = t; bb < NB; bb += 256) {
    s1 += bn_part[(size_t)bb * 64 + c];
    s2 += bn_part[(size_t)bb * 64 + c + 32];
  }
  #pragma unroll
  for (int mask = 1; mask <= 32; mask <<= 1) {
    s1 += __shfl_xor(s1, mask);
    s2 += __shfl_xor(s2, mask);
  }
  if (lane == 0) { red[0][w] = s1; red[1][w] = s2; }
  __syncthreads();
  if (t == 0) {
    float S1 = red[0][0] + red[0][1] + red[0][2] + red[0][3];
    float S2 = red[1][0] + red[1][1] + red[1][2] + red[1][3];
    const float inv = 1.f / (float)(NB * 128);
    float mean = S1 * inv;
    float var = S2 * inv - mean * mean;
    float scl = gamma[c] * rsqrtf(var + 1e-5f);
    coef[c] = scl;
    coef[32 + c] = beta[c] - mean * scl;
  }
}

// ---------------------------------------------------------------- k3: BN apply + residual + leaky (bf16 feat -> f32 out)
__global__ __launch_bounds__(256) void k3_final(const float* __restrict__ xg,
                                                const unsigned int* __restrict__ feat16,
                                                float* __restrict__ out,
                                                const float* __restrict__ coef) {
  __shared__ float s_c[64];
  if (threadIdx.x < 64) s_c[threadIdx.x] = coef[threadIdx.x];
  __syncthreads();
  size_t i4 = (size_t)blockIdx.x * 256 + threadIdx.x;  // covers 4 channels
  uint2 fu = ((const uint2*)feat16)[i4];
  float4 x = ((const float4*)xg)[i4];
  int c = (int)((i4 * 4) & 31);
  float4 r;
  r.x = x.x + bflo(fu.x) * s_c[c + 0] + s_c[32 + c + 0];
  r.y = x.y + bfhi(fu.x) * s_c[c + 1] + s_c[32 + c + 1];
  r.z = x.z + bflo(fu.y) * s_c[c + 2] + s_c[32 + c + 2];
  r.w = x.w + bfhi(fu.y) * s_c[c + 3] + s_c[32 + c + 3];
  r.x = r.x >= 0.f ? r.x : 0.2f * r.x;
  r.y = r.y >= 0.f ? r.y : 0.2f * r.y;
  r.z = r.z >= 0.f ? r.z : 0.2f * r.z;
  r.w = r.w >= 0.f ? r.w : 0.2f * r.w;
  ((float4*)out)[i4] = r;
}

// ----------------------------------------------------------------
extern "C" void kernel_launch(void* const* d_in, const int* in_sizes, int n_in,
                              void* d_out, int out_size, void* d_ws, size_t ws_size,
                              hipStream_t stream) {
  const float* xg    = (const float*)d_in[0];
  const float* xl    = (const float*)d_in[1];
  const float* W_lin = (const float*)d_in[2];
  const float* b_lin = (const float*)d_in[3];
  const float* W_att = (const float*)d_in[4];
  const float* Wa    = (const float*)d_in[5];
  const float* Wb    = (const float*)d_in[6];
  const float* Wc    = (const float*)d_in[7];
  const float* Wn    = (const float*)d_in[8];
  const float* Wl    = (const float*)d_in[9];
  const float* Wd    = (const float*)d_in[10];
  const float* gamma = (const float*)d_in[11];
  const float* beta  = (const float*)d_in[12];
  float* out = (float*)d_out;
  float* ws = (float*)d_ws;
  float* pre = ws;
  float* bn_part = ws + WS_BNPART;
  float* coef = ws + WS_COEF;
  unsigned int* feat16 = (unsigned int*)(ws + WS_FEAT16);

  hipLaunchKernelGGL(k0_pre, dim3(1), dim3(256), 0, stream,
                     W_lin, b_lin, W_att, Wa, Wb, Wn, Wl, pre);
  hipLaunchKernelGGL(k1_merged, dim3(NB), dim3(1024), 0, stream,
                     xl, xg, pre, Wc, Wd, feat16, bn_part);
  hipLaunchKernelGGL(k2_stats, dim3(32), dim3(256), 0, stream, bn_part, gamma, beta, coef);
  hipLaunchKernelGGL(k3_final, dim3(8192), dim3(256), 0, stream, xg, feat16, out, coef);
}

// Round 12
// 195.871 us; speedup vs baseline: 1.2563x; 1.2563x over previous
//
#include <hip/hip_runtime.h>
#include <math.h>

#define NB 2048
typedef float f32x4 __attribute__((ext_vector_type(4)));
typedef float f32x2 __attribute__((ext_vector_type(2)));

// pre[] float offsets (folded weights)
#define P_WAL 0
#define P_WBL 1024
#define P_WLBL 2048
#define P_WNAL 3072
#define P_WEFF 4096
#define P_BWA 4160
#define P_BWB 4176
#define P_BWL 4192
#define P_BWN 4208
#define P_C0  4224

// ws float offsets
#define WS_BNPART 4352
#define WS_COEF   135424
#define WS_SMALL  135488                  // [2048][160]
#define WS_BIG_I  463168                  // [2048][2048] f32: intra2T rows [s][16]
#define WS_BIG_V  (463168 + 4194304)      // [2048][2048] f32: v_intra rows [s][16]
#define WS_FEAT16 (463168 + 8388608)      // [2048][128][32] bf16

__device__ __forceinline__ unsigned short f2bf(float f) {
  unsigned int u = __float_as_uint(f);
  u += 0x7fffu + ((u >> 16) & 1u);
  return (unsigned short)(u >> 16);
}
__device__ __forceinline__ unsigned int pack2bf(float lo, float hi) {
  return (unsigned int)f2bf(lo) | ((unsigned int)f2bf(hi) << 16);
}
__device__ __forceinline__ float bflo(unsigned int u) { return __uint_as_float(u << 16); }
__device__ __forceinline__ float bfhi(unsigned int u) { return __uint_as_float(u & 0xffff0000u); }

#define BSTAGE(MASK, HALF)                                        \
  { const bool hi_ = (lane & (MASK)) != 0;                        \
    _Pragma("unroll")                                             \
    for (int k_ = 0; k_ < (HALF); ++k_) {                         \
      float mine_ = hi_ ? a[k_ + (HALF)] : a[k_];                 \
      float oth_  = hi_ ? a[k_] : a[k_ + (HALF)];                 \
      a[k_] = mine_ + __shfl_xor(oth_, (MASK));                   \
    } }

// ---------------------------------------------------------------- k0: fold weights
__global__ __launch_bounds__(256) void k0_pre(const float* __restrict__ W_lin,
                                              const float* __restrict__ b_lin,
                                              const float* __restrict__ W_att,
                                              const float* __restrict__ Wa,
                                              const float* __restrict__ Wb,
                                              const float* __restrict__ Wn,
                                              const float* __restrict__ Wl,
                                              float* __restrict__ pre) {
  int t = threadIdx.x;
  for (int i = t; i < 1024; i += 256) {
    int o = i >> 6, d = i & 63;
    float sa = 0.f, sb = 0.f;
    for (int c = 0; c < 32; ++c) {
      float wl = W_lin[c * 64 + d];
      sa += Wa[o * 32 + c] * wl;
      sb += Wb[o * 32 + c] * wl;
    }
    pre[P_WAL + i] = sa;
    pre[P_WBL + i] = sb;
  }
  if (t < 64) {
    float s = 0.f;
    for (int c = 0; c < 32; ++c) s += W_att[c] * W_lin[c * 64 + t];
    pre[P_WEFF + t] = s;
  }
  if (t < 16) {
    float sa = 0.f, sb = 0.f;
    for (int c = 0; c < 32; ++c) {
      sa += Wa[t * 32 + c] * b_lin[c];
      sb += Wb[t * 32 + c] * b_lin[c];
    }
    pre[P_BWA + t] = sa;
    pre[P_BWB + t] = sb;
  }
  if (t == 0) {
    float s = 0.f;
    for (int c = 0; c < 32; ++c) s += W_att[c] * b_lin[c];
    pre[P_C0] = s;
  }
  __syncthreads();
  for (int i = t; i < 1024; i += 256) {
    int p_ = i >> 6, d = i & 63;
    float sl = 0.f, sn = 0.f;
    for (int o = 0; o < 16; ++o) {
      sl += Wl[p_ * 16 + o] * pre[P_WBL + o * 64 + d];
      sn += Wn[p_ * 16 + o] * pre[P_WAL + o * 64 + d];
    }
    pre[P_WLBL + i] = sl;
    pre[P_WNAL + i] = sn;
  }
  if (t < 16) {
    float sl = 0.f, sn = 0.f;
    for (int o = 0; o < 16; ++o) {
      sl += Wl[t * 16 + o] * pre[P_BWB + o];
      sn += Wn[t * 16 + o] * pre[P_BWA + o];
    }
    pre[P_BWL + t] = sl;
    pre[P_BWN + t] = sn;
  }
}

// ---------------------------------------------------------------- k1a: R10-proven (1024 threads, 2 rows/thread)
__global__ __launch_bounds__(1024, 2) void k1a(
    const float* __restrict__ xl_all, const float* __restrict__ pre,
    float* __restrict__ p_small, float* __restrict__ bigI,
    float* __restrict__ bigV) {
  __shared__ __align__(16) float xaggi[128 * 68];   // 34816 B
  __shared__ f32x4 scratch5[5][16][16];             // 20480 B
  __shared__ float pe[5][16];
  __shared__ float xagg_inter[5][64];

  const int t = threadIdx.x;
  const int b = blockIdx.x;
  const int lane = t & 63;
  const int w = t >> 6;                 // 16 waves; wave owns rows 8w..8w+7
  const int q = lane >> 4;
  const int i16 = lane & 15;

  const float* xl = xl_all + (size_t)b * (5 * 128 * 64);
  const f32x4 weff4 = ((const f32x4*)(pre + P_WEFF))[i16];
  const float c0 = pre[P_C0];

  const float* xb = xl + (size_t)(8 * w + q) * 64 + 4 * i16;

  f32x4 xA[2], xB[2], acc[2];
  float Zk[2];
  #pragma unroll
  for (int k = 0; k < 2; ++k) {
    acc[k] = (f32x4)0.f;
    Zk[k] = 0.f;
    xA[k] = *(const f32x4*)(xb + k * 256);
  }

  #pragma unroll
  for (int m = 0; m < 5; ++m) {
    f32x4* xc = (m & 1) ? xB : xA;
    f32x4* xn = (m & 1) ? xA : xB;
    if (m < 4) {
      const float* np = xb + (size_t)(m + 1) * 8192;
      #pragma unroll
      for (int k = 0; k < 2; ++k) xn[k] = *(const f32x4*)(np + k * 256);
    }
    float a0, a1;
    {
      f32x4 p0 = xc[0] * weff4, p1 = xc[1] * weff4;
      a0 = p0.x + p0.y + p0.z + p0.w;
      a1 = p1.x + p1.y + p1.z + p1.w;
    }
    #pragma unroll
    for (int mask = 1; mask <= 8; mask <<= 1) {
      a0 += __shfl_xor(a0, mask);
      a1 += __shfl_xor(a1, mask);
    }
    float e0 = __expf(a0 + c0), e1 = __expf(a1 + c0);
    Zk[0] += e0; Zk[1] += e1;
    f32x4 pim;
    {
      f32x4 pr0 = e0 * xc[0];
      f32x4 pr1 = e1 * xc[1];
      acc[0] += pr0; acc[1] += pr1;
      pim = pr0 + pr1;
    }
    float se = e0 + e1;
    #pragma unroll
    for (int mask = 16; mask <= 32; mask <<= 1) {
      pim.x += __shfl_xor(pim.x, mask);
      pim.y += __shfl_xor(pim.y, mask);
      pim.z += __shfl_xor(pim.z, mask);
      pim.w += __shfl_xor(pim.w, mask);
      se += __shfl_xor(se, mask);
    }
    if (lane < 16) {
      scratch5[m][w][i16] = pim;
      if (i16 == 0) pe[m][w] = se;
    }
  }

  #pragma unroll
  for (int k = 0; k < 2; ++k) {
    float invz = 1.f / Zk[k];
    f32x4 v = acc[k] * invz;
    int r = 8 * w + 4 * k + q;
    *(f32x4*)&xaggi[r * 68 + 4 * i16] = v;
  }
  __syncthreads();

  if (t < 320) {
    int mm = t >> 6, d = t & 63;
    const float* sp = (const float*)&scratch5[mm][0][0];
    float s = 0.f;
    #pragma unroll
    for (int j = 0; j < 16; ++j) s += sp[j * 64 + d];
    float sume = 0.f;
    #pragma unroll
    for (int j = 0; j < 16; ++j) sume += pe[mm][j];
    xagg_inter[mm][d] = s / sume;
  }
  __syncthreads();

  if (t < 512) {
    const int q2 = __builtin_amdgcn_readfirstlane(t >> 7);
    const int s2 = t & 127;
    const float* Wbase = pre + ((q2 < 2) ? P_WBL : P_WLBL) + (q2 & 1) * 512;
    const float* xrow = &xaggi[s2 * 68];
    float acc2[8];
    #pragma unroll
    for (int r = 0; r < 8; ++r) acc2[r] = 0.f;
    #pragma unroll
    for (int c = 0; c < 64; c += 4) {
      f32x4 xa = *(const f32x4*)(xrow + c);
      #pragma unroll
      for (int r = 0; r < 8; ++r)
        acc2[r] += xa.x * Wbase[r * 64 + c] + xa.y * Wbase[r * 64 + c + 1] +
                   xa.z * Wbase[r * 64 + c + 2] + xa.w * Wbase[r * 64 + c + 3];
    }
    const int bb = ((q2 < 2) ? P_BWB : P_BWL) + (q2 & 1) * 8;
    float* dst = ((q2 < 2) ? bigI : bigV) + (size_t)b * 2048 + s2 * 16 + (q2 & 1) * 8;
    f32x4 o0, o1;
    o0.x = acc2[0] + pre[bb + 0];
    o0.y = acc2[1] + pre[bb + 1];
    o0.z = acc2[2] + pre[bb + 2];
    o0.w = acc2[3] + pre[bb + 3];
    o1.x = acc2[4] + pre[bb + 4];
    o1.y = acc2[5] + pre[bb + 5];
    o1.z = acc2[6] + pre[bb + 6];
    o1.w = acc2[7] + pre[bb + 7];
    *(f32x4*)dst = o0;
    *(f32x4*)(dst + 4) = o1;
  } else if (t < 672) {
    int tt = t - 512;
    int o2 = tt & 31, mm = tt >> 5;
    const float* wr = pre + ((o2 < 16) ? (P_WAL + o2 * 64) : (P_WNAL + (o2 - 16) * 64));
    float p = 0.f;
    #pragma unroll
    for (int d = 0; d < 64; ++d) p += wr[d] * xagg_inter[mm][d];
    p += (o2 < 16) ? pre[P_BWA + o2] : pre[P_BWN + (o2 - 16)];
    float* os = p_small + (size_t)b * 160;
    if (o2 < 16) os[mm * 16 + o2] = p;
    else os[80 + mm * 16 + (o2 - 16)] = p;
  }
}

// ---------------------------------------------------------------- k1b: attention, i-partitioned over 4 waves (256 threads)
__global__ __launch_bounds__(256, 4) void k1b(
    const float* __restrict__ xg_all, const float* __restrict__ Wc_g,
    const float* __restrict__ Wd_g, const float* __restrict__ p_small,
    const float* __restrict__ bigI, const float* __restrict__ bigV,
    unsigned int* __restrict__ feat16, float* __restrict__ bn_part) {
  // union region: phase A = slabI[128][20] | slabV[128][20] | xlogL[128][20]  (30720 B)
  //               phase B = comb[4][128][20]                                  (40960 B)
  __shared__ __align__(16) float UN[10240];
  float* slabI = UN;            // [128][20], cols 0..15 used
  float* slabV = UN + 2560;
  float* xlogL = UN + 5120;
  __shared__ float s_sm[160];
  __shared__ float part1[2][32];
  __shared__ float part2[2][32];

  const int t = threadIdx.x;
  const int b = blockIdx.x;
  const int lane = t & 63;
  const int w = t >> 6;              // 4 waves; wave w owns i in [32w, 32w+32)

  // ---- stage A: slabs (pitch 20), xlog rows, s_sm
  {
    const f32x4* gI = (const f32x4*)(bigI + (size_t)b * 2048);
    const f32x4* gV = (const f32x4*)(bigV + (size_t)b * 2048);
    #pragma unroll
    for (int j = 0; j < 2; ++j) {
      int idx = t + 256 * j;           // 0..511
      int row = idx >> 2, c4 = idx & 3;
      *(f32x4*)&slabI[row * 20 + 4 * c4] = gI[idx];
      *(f32x4*)&slabV[row * 20 + 4 * c4] = gV[idx];
    }
  }
  if (t < 128) {
    const int n = t;
    const f32x4* xgr = (const f32x4*)(xg_all + ((size_t)b * 128 + n) * 32);
    f32x4 xv[8];
    #pragma unroll
    for (int j = 0; j < 8; ++j) xv[j] = xgr[j];
    #pragma unroll
    for (int o4 = 0; o4 < 4; ++o4) {
      f32x4 r;
      #pragma unroll
      for (int jj = 0; jj < 4; ++jj) {
        const int o = o4 * 4 + jj;
        f32x4 s = (f32x4)0.f;
        #pragma unroll
        for (int j = 0; j < 8; ++j) s += xv[j] * *(const f32x4*)(Wc_g + o * 32 + 4 * j);
        r[jj] = s.x + s.y + s.z + s.w;
      }
      *(f32x4*)&xlogL[n * 20 + 4 * o4] = r;
    }
  }
  if (t >= 96) {
    int i2 = t - 96;                   // 0..159
    s_sm[i2] = p_small[(size_t)b * 160 + i2];
  }
  __syncthreads();  // bar1

  // ---- reg-load xlog for this lane's two n
  const int n0 = lane, n1 = lane + 64;
  f32x4 xlg0[4], xlg1[4];
  #pragma unroll
  for (int c = 0; c < 4; ++c) {
    xlg0[c] = *(const f32x4*)&xlogL[n0 * 20 + 4 * c];
    xlg1[c] = *(const f32x4*)&xlogL[n1 * 20 + 4 * c];
  }

  // ---- i-loop: wave-uniform slab rows (broadcast reads), 32 iters
  float s0 = 0.f, s1 = 0.f;
  f32x4 fav0[4], fav1[4];
  #pragma unroll
  for (int c = 0; c < 4; ++c) { fav0[c] = (f32x4)0.f; fav1[c] = (f32x4)0.f; }
  for (int k = 0; k < 32; ++k) {
    const int i = 32 * w + k;
    const f32x4* rI = (const f32x4*)&slabI[i * 20];
    f32x4 d0 = xlg0[0] * rI[0] + xlg0[1] * rI[1] + xlg0[2] * rI[2] + xlg0[3] * rI[3];
    f32x4 d1 = xlg1[0] * rI[0] + xlg1[1] * rI[1] + xlg1[2] * rI[2] + xlg1[3] * rI[3];
    float e0 = __expf(d0.x + d0.y + d0.z + d0.w);
    float e1 = __expf(d1.x + d1.y + d1.z + d1.w);
    s0 += e0; s1 += e1;
    const f32x4* rV = (const f32x4*)&slabV[i * 20];
    #pragma unroll
    for (int c = 0; c < 4; ++c) {
      f32x4 v = rV[c];
      fav0[c] += e0 * v;
      fav1[c] += e1 * v;
    }
  }
  __syncthreads();  // bar2 (slabs + xlogL dead)

  // ---- write per-wave partials into comb[w] (overlays UN)
  {
    float* c0p = UN + w * 2560 + n0 * 20;
    float* c1p = UN + w * 2560 + n1 * 20;
    #pragma unroll
    for (int c = 0; c < 4; ++c) {
      *(f32x4*)&c0p[4 * c] = fav0[c];
      *(f32x4*)&c1p[4 * c] = fav1[c];
    }
    c0p[16] = s0;
    c1p[16] = s1;
  }
  __syncthreads();  // bar3

  // ---- combine 4 wave-partials: thread (n = t&127, g = t>>7)
  {
    const int n = t & 127, g = t >> 7;       // g=0: cols 0..7, g=1: cols 8..16
    if (g == 0) {
      f32x4 a0 = (f32x4)0.f, a1 = (f32x4)0.f;
      #pragma unroll
      for (int ww = 0; ww < 4; ++ww) {
        const float* cp = UN + ww * 2560 + n * 20;
        a0 += *(const f32x4*)&cp[0];
        a1 += *(const f32x4*)&cp[4];
      }
      float* dp = UN + n * 20;
      *(f32x4*)&dp[0] = a0;
      *(f32x4*)&dp[4] = a1;
    } else {
      f32x4 a2 = (f32x4)0.f, a3 = (f32x4)0.f;
      float as = 0.f;
      #pragma unroll
      for (int ww = 0; ww < 4; ++ww) {
        const float* cp = UN + ww * 2560 + n * 20;
        a2 += *(const f32x4*)&cp[8];
        a3 += *(const f32x4*)&cp[12];
        as += cp[16];
      }
      float* dp = UN + n * 20;
      *(f32x4*)&dp[8] = a2;
      *(f32x4*)&dp[12] = a3;
      dp[16] = as;
    }
  }
  __syncthreads();  // bar4

  // ---- tail (threads 0..127): fin, f_inter, feat, BN partials (R10-proven structure)
  if (t < 128) {
    const int n = t;
    const float* cp = UN + n * 20;
    f32x4 fav[4];
    #pragma unroll
    for (int c = 0; c < 4; ++c) fav[c] = *(const f32x4*)&cp[4 * c];
    const float inv = 1.f / cp[16];
    f32x4 fin[4];
    #pragma unroll
    for (int c = 0; c < 4; ++c) fin[c] = fav[c] * inv;

    // this thread's xlog: wave0 lane t -> n0 = t; wave1 lane t-64 -> n1 = t
    f32x4 xme[4];
    #pragma unroll
    for (int c = 0; c < 4; ++c) xme[c] = (t < 64) ? xlg0[c] : xlg1[c];

    float L[5], mx3 = -1e30f;
    #pragma unroll
    for (int mm = 0; mm < 5; ++mm) {
      float p = 0.f;
      #pragma unroll
      for (int c = 0; c < 4; ++c) {
        #pragma unroll
        for (int jj = 0; jj < 4; ++jj) p += xme[c][jj] * s_sm[mm * 16 + 4 * c + jj];
      }
      L[mm] = p;
      mx3 = fmaxf(mx3, p);
    }
    float sum3 = 0.f;
    #pragma unroll
    for (int mm = 0; mm < 5; ++mm) { L[mm] = __expf(L[mm] - mx3); sum3 += L[mm]; }
    const float inv3 = 1.f / sum3;
    f32x4 fi[4];
    #pragma unroll
    for (int o4 = 0; o4 < 4; ++o4) {
      f32x4 r;
      #pragma unroll
      for (int jj = 0; jj < 4; ++jj) {
        float p = 0.f;
        #pragma unroll
        for (int mm = 0; mm < 5; ++mm) p += L[mm] * s_sm[80 + mm * 16 + o4 * 4 + jj];
        r[jj] = p * inv3;
      }
      fi[o4] = r;
    }

    f32x4 feat[8];
    #pragma unroll
    for (int o4 = 0; o4 < 8; ++o4) {
      f32x4 r;
      #pragma unroll
      for (int jj = 0; jj < 4; ++jj) {
        const int o = o4 * 4 + jj;
        f32x4 s = (f32x4)0.f;
        #pragma unroll
        for (int j = 0; j < 4; ++j) {
          s += fi[j]  * *(const f32x4*)(Wd_g + o * 32 + 4 * j);
          s += fin[j] * *(const f32x4*)(Wd_g + o * 32 + 16 + 4 * j);
        }
        r[jj] = s.x + s.y + s.z + s.w;
      }
      feat[o4] = r;
    }
    {
      unsigned int* op = feat16 + ((size_t)b * 128 + n) * 16;
      uint4 u0, u1, u2, u3;
      u0.x = pack2bf(feat[0].x, feat[0].y); u0.y = pack2bf(feat[0].z, feat[0].w);
      u0.z = pack2bf(feat[1].x, feat[1].y); u0.w = pack2bf(feat[1].z, feat[1].w);
      u1.x = pack2bf(feat[2].x, feat[2].y); u1.y = pack2bf(feat[2].z, feat[2].w);
      u1.z = pack2bf(feat[3].x, feat[3].y); u1.w = pack2bf(feat[3].z, feat[3].w);
      u2.x = pack2bf(feat[4].x, feat[4].y); u2.y = pack2bf(feat[4].z, feat[4].w);
      u2.z = pack2bf(feat[5].x, feat[5].y); u2.w = pack2bf(feat[5].z, feat[5].w);
      u3.x = pack2bf(feat[6].x, feat[6].y); u3.y = pack2bf(feat[6].z, feat[6].w);
      u3.z = pack2bf(feat[7].x, feat[7].y); u3.w = pack2bf(feat[7].z, feat[7].w);
      ((uint4*)op)[0] = u0;
      ((uint4*)op)[1] = u1;
      ((uint4*)op)[2] = u2;
      ((uint4*)op)[3] = u3;
    }

    const int w2 = t >> 6;   // 0 or 1
    const int kmap = ((lane & 1) << 4) | ((lane & 2) << 2) | (lane & 4) |
                     ((lane >> 2) & 2) | ((lane >> 4) & 1);
    {
      float a[32];
      #pragma unroll
      for (int o = 0; o < 32; ++o) a[o] = feat[o >> 2][o & 3];
      BSTAGE(1, 16) BSTAGE(2, 8) BSTAGE(4, 4) BSTAGE(8, 2) BSTAGE(16, 1)
      a[0] += __shfl_xor(a[0], 32);
      if (lane < 32) part1[w2][kmap] = a[0];
    }
    {
      float a[32];
      #pragma unroll
      for (int o = 0; o < 32; ++o) { float v = feat[o >> 2][o & 3]; a[o] = v * v; }
      BSTAGE(1, 16) BSTAGE(2, 8) BSTAGE(4, 4) BSTAGE(8, 2) BSTAGE(16, 1)
      a[0] += __shfl_xor(a[0], 32);
      if (lane < 32) part2[w2][kmap] = a[0];
    }
  }
  __syncthreads();  // bar5
  if (t < 64) {
    int c = t & 31, h = t >> 5;
    float v = h ? (part2[0][c] + part2[1][c]) : (part1[0][c] + part1[1][c]);
    bn_part[(size_t)b * 64 + h * 32 + c] = v;
  }
}

// ---------------------------------------------------------------- k2: BN coefficients (one block per channel)
__global__ __launch_bounds__(256, 1) void k2_stats(const float* __restrict__ bn_part,
                                                   const float* __restrict__ gamma,
                                                   const float* __restrict__ beta,
                                                   float* __restrict__ coef) {
  __shared__ float red[2][4];
  const int c = blockIdx.x;
  const int t = threadIdx.x;
  const int lane = t & 63, w = t >> 6;
  float s1 = 0.f, s2 = 0.f;
  for (int bb = t; bb < NB; bb += 256) {
    s1 += bn_part[(size_t)bb * 64 + c];
    s2 += bn_part[(size_t)bb * 64 + c + 32];
  }
  #pragma unroll
  for (int mask = 1; mask <= 32; mask <<= 1) {
    s1 += __shfl_xor(s1, mask);
    s2 += __shfl_xor(s2, mask);
  }
  if (lane == 0) { red[0][w] = s1; red[1][w] = s2; }
  __syncthreads();
  if (t == 0) {
    float S1 = red[0][0] + red[0][1] + red[0][2] + red[0][3];
    float S2 = red[1][0] + red[1][1] + red[1][2] + red[1][3];
    const float inv = 1.f / (float)(NB * 128);
    float mean = S1 * inv;
    float var = S2 * inv - mean * mean;
    float scl = gamma[c] * rsqrtf(var + 1e-5f);
    coef[c] = scl;
    coef[32 + c] = beta[c] - mean * scl;
  }
}

// ---------------------------------------------------------------- k3: BN apply + residual + leaky (bf16 feat -> f32 out)
__global__ __launch_bounds__(256) void k3_final(const float* __restrict__ xg,
                                                const unsigned int* __restrict__ feat16,
                                                float* __restrict__ out,
                                                const float* __restrict__ coef) {
  __shared__ float s_c[64];
  if (threadIdx.x < 64) s_c[threadIdx.x] = coef[threadIdx.x];
  __syncthreads();
  size_t i4 = (size_t)blockIdx.x * 256 + threadIdx.x;
  uint2 fu = ((const uint2*)feat16)[i4];
  float4 x = ((const float4*)xg)[i4];
  int c = (int)((i4 * 4) & 31);
  float4 r;
  r.x = x.x + bflo(fu.x) * s_c[c + 0] + s_c[32 + c + 0];
  r.y = x.y + bfhi(fu.x) * s_c[c + 1] + s_c[32 + c + 1];
  r.z = x.z + bflo(fu.y) * s_c[c + 2] + s_c[32 + c + 2];
  r.w = x.w + bfhi(fu.y) * s_c[c + 3] + s_c[32 + c + 3];
  r.x = r.x >= 0.f ? r.x : 0.2f * r.x;
  r.y = r.y >= 0.f ? r.y : 0.2f * r.y;
  r.z = r.z >= 0.f ? r.z : 0.2f * r.z;
  r.w = r.w >= 0.f ? r.w : 0.2f * r.w;
  ((float4*)out)[i4] = r;
}

// ----------------------------------------------------------------
extern "C" void kernel_launch(void* const* d_in, const int* in_sizes, int n_in,
                              void* d_out, int out_size, void* d_ws, size_t ws_size,
                              hipStream_t stream) {
  const float* xg    = (const float*)d_in[0];
  const float* xl    = (const float*)d_in[1];
  const float* W_lin = (const float*)d_in[2];
  const float* b_lin = (const float*)d_in[3];
  const float* W_att = (const float*)d_in[4];
  const float* Wa    = (const float*)d_in[5];
  const float* Wb    = (const float*)d_in[6];
  const float* Wc    = (const float*)d_in[7];
  const float* Wn    = (const float*)d_in[8];
  const float* Wl    = (const float*)d_in[9];
  const float* Wd    = (const float*)d_in[10];
  const float* gamma = (const float*)d_in[11];
  const float* beta  = (const float*)d_in[12];
  float* out = (float*)d_out;
  float* ws = (float*)d_ws;
  float* pre = ws;
  float* bn_part = ws + WS_BNPART;
  float* coef = ws + WS_COEF;
  float* p_small = ws + WS_SMALL;
  float* bigI = ws + WS_BIG_I;
  float* bigV = ws + WS_BIG_V;
  unsigned int* feat16 = (unsigned int*)(ws + WS_FEAT16);

  hipLaunchKernelGGL(k0_pre, dim3(1), dim3(256), 0, stream,
                     W_lin, b_lin, W_att, Wa, Wb, Wn, Wl, pre);
  hipLaunchKernelGGL(k1a, dim3(NB), dim3(1024), 0, stream, xl, pre, p_small, bigI, bigV);
  hipLaunchKernelGGL(k1b, dim3(NB), dim3(256), 0, stream,
                     xg, Wc, Wd, p_small, bigI, bigV, feat16, bn_part);
  hipLaunchKernelGGL(k2_stats, dim3(32), dim3(256), 0, stream, bn_part, gamma, beta, coef);
  hipLaunchKernelGGL(k3_final, dim3(8192), dim3(256), 0, stream, xg, feat16, out, coef);
}

// Round 13
// 191.024 us; speedup vs baseline: 1.2882x; 1.0254x over previous
//
#include <hip/hip_runtime.h>
#include <math.h>

#define NB 2048
typedef float f32x4 __attribute__((ext_vector_type(4)));
typedef float f32x2 __attribute__((ext_vector_type(2)));
typedef short s16x8 __attribute__((ext_vector_type(8)));

// pre[] float offsets (folded weights)
#define P_WAL 0
#define P_WBL 1024
#define P_WLBL 2048
#define P_WNAL 3072
#define P_WEFF 4096
#define P_BWA 4160
#define P_BWB 4176
#define P_BWL 4192
#define P_BWN 4208
#define P_C0  4224

// ws float offsets
#define WS_BNPART 4352
#define WS_COEF   135424
#define WS_SMALL  135488                  // [2048][160]
#define WS_BIG_I  463168                  // [2048][2048] f32: intra2T rows [s][16]
#define WS_BIG_V  (463168 + 4194304)      // [2048][2048] f32: v_intra rows [s][16]
#define WS_FEAT16 (463168 + 8388608)      // [2048][128][32] bf16

__device__ __forceinline__ unsigned short f2bf(float f) {
  unsigned int u = __float_as_uint(f);
  u += 0x7fffu + ((u >> 16) & 1u);
  return (unsigned short)(u >> 16);
}
__device__ __forceinline__ unsigned int pack2bf(float lo, float hi) {
  return (unsigned int)f2bf(lo) | ((unsigned int)f2bf(hi) << 16);
}
__device__ __forceinline__ float bflo(unsigned int u) { return __uint_as_float(u << 16); }
__device__ __forceinline__ float bfhi(unsigned int u) { return __uint_as_float(u & 0xffff0000u); }

#define BSTAGE(MASK, HALF)                                        \
  { const bool hi_ = (lane & (MASK)) != 0;                        \
    _Pragma("unroll")                                             \
    for (int k_ = 0; k_ < (HALF); ++k_) {                         \
      float mine_ = hi_ ? a[k_ + (HALF)] : a[k_];                 \
      float oth_  = hi_ ? a[k_] : a[k_ + (HALF)];                 \
      a[k_] = mine_ + __shfl_xor(oth_, (MASK));                   \
    } }

// ---------------------------------------------------------------- k0: fold weights (R12-verbatim)
__global__ __launch_bounds__(256) void k0_pre(const float* __restrict__ W_lin,
                                              const float* __restrict__ b_lin,
                                              const float* __restrict__ W_att,
                                              const float* __restrict__ Wa,
                                              const float* __restrict__ Wb,
                                              const float* __restrict__ Wn,
                                              const float* __restrict__ Wl,
                                              float* __restrict__ pre) {
  int t = threadIdx.x;
  for (int i = t; i < 1024; i += 256) {
    int o = i >> 6, d = i & 63;
    float sa = 0.f, sb = 0.f;
    for (int c = 0; c < 32; ++c) {
      float wl = W_lin[c * 64 + d];
      sa += Wa[o * 32 + c] * wl;
      sb += Wb[o * 32 + c] * wl;
    }
    pre[P_WAL + i] = sa;
    pre[P_WBL + i] = sb;
  }
  if (t < 64) {
    float s = 0.f;
    for (int c = 0; c < 32; ++c) s += W_att[c] * W_lin[c * 64 + t];
    pre[P_WEFF + t] = s;
  }
  if (t < 16) {
    float sa = 0.f, sb = 0.f;
    for (int c = 0; c < 32; ++c) {
      sa += Wa[t * 32 + c] * b_lin[c];
      sb += Wb[t * 32 + c] * b_lin[c];
    }
    pre[P_BWA + t] = sa;
    pre[P_BWB + t] = sb;
  }
  if (t == 0) {
    float s = 0.f;
    for (int c = 0; c < 32; ++c) s += W_att[c] * b_lin[c];
    pre[P_C0] = s;
  }
  __syncthreads();
  for (int i = t; i < 1024; i += 256) {
    int p_ = i >> 6, d = i & 63;
    float sl = 0.f, sn = 0.f;
    for (int o = 0; o < 16; ++o) {
      sl += Wl[p_ * 16 + o] * pre[P_WBL + o * 64 + d];
      sn += Wn[p_ * 16 + o] * pre[P_WAL + o * 64 + d];
    }
    pre[P_WLBL + i] = sl;
    pre[P_WNAL + i] = sn;
  }
  if (t < 16) {
    float sl = 0.f, sn = 0.f;
    for (int o = 0; o < 16; ++o) {
      sl += Wl[t * 16 + o] * pre[P_BWB + o];
      sn += Wn[t * 16 + o] * pre[P_BWA + o];
    }
    pre[P_BWL + t] = sl;
    pre[P_BWN + t] = sn;
  }
}

// ---------------------------------------------------------------- k1a: R10/R12-proven (1024 threads, 2 rows/thread)
__global__ __launch_bounds__(1024, 2) void k1a(
    const float* __restrict__ xl_all, const float* __restrict__ pre,
    float* __restrict__ p_small, float* __restrict__ bigI,
    float* __restrict__ bigV) {
  __shared__ __align__(16) float xaggi[128 * 68];
  __shared__ f32x4 scratch5[5][16][16];
  __shared__ float pe[5][16];
  __shared__ float xagg_inter[5][64];

  const int t = threadIdx.x;
  const int b = blockIdx.x;
  const int lane = t & 63;
  const int w = t >> 6;
  const int q = lane >> 4;
  const int i16 = lane & 15;

  const float* xl = xl_all + (size_t)b * (5 * 128 * 64);
  const f32x4 weff4 = ((const f32x4*)(pre + P_WEFF))[i16];
  const float c0 = pre[P_C0];

  const float* xb = xl + (size_t)(8 * w + q) * 64 + 4 * i16;

  f32x4 xA[2], xB[2], acc[2];
  float Zk[2];
  #pragma unroll
  for (int k = 0; k < 2; ++k) {
    acc[k] = (f32x4)0.f;
    Zk[k] = 0.f;
    xA[k] = *(const f32x4*)(xb + k * 256);
  }

  #pragma unroll
  for (int m = 0; m < 5; ++m) {
    f32x4* xc = (m & 1) ? xB : xA;
    f32x4* xn = (m & 1) ? xA : xB;
    if (m < 4) {
      const float* np = xb + (size_t)(m + 1) * 8192;
      #pragma unroll
      for (int k = 0; k < 2; ++k) xn[k] = *(const f32x4*)(np + k * 256);
    }
    float a0, a1;
    {
      f32x4 p0 = xc[0] * weff4, p1 = xc[1] * weff4;
      a0 = p0.x + p0.y + p0.z + p0.w;
      a1 = p1.x + p1.y + p1.z + p1.w;
    }
    #pragma unroll
    for (int mask = 1; mask <= 8; mask <<= 1) {
      a0 += __shfl_xor(a0, mask);
      a1 += __shfl_xor(a1, mask);
    }
    float e0 = __expf(a0 + c0), e1 = __expf(a1 + c0);
    Zk[0] += e0; Zk[1] += e1;
    f32x4 pim;
    {
      f32x4 pr0 = e0 * xc[0];
      f32x4 pr1 = e1 * xc[1];
      acc[0] += pr0; acc[1] += pr1;
      pim = pr0 + pr1;
    }
    float se = e0 + e1;
    #pragma unroll
    for (int mask = 16; mask <= 32; mask <<= 1) {
      pim.x += __shfl_xor(pim.x, mask);
      pim.y += __shfl_xor(pim.y, mask);
      pim.z += __shfl_xor(pim.z, mask);
      pim.w += __shfl_xor(pim.w, mask);
      se += __shfl_xor(se, mask);
    }
    if (lane < 16) {
      scratch5[m][w][i16] = pim;
      if (i16 == 0) pe[m][w] = se;
    }
  }

  #pragma unroll
  for (int k = 0; k < 2; ++k) {
    float invz = 1.f / Zk[k];
    f32x4 v = acc[k] * invz;
    int r = 8 * w + 4 * k + q;
    *(f32x4*)&xaggi[r * 68 + 4 * i16] = v;
  }
  __syncthreads();

  if (t < 320) {
    int mm = t >> 6, d = t & 63;
    const float* sp = (const float*)&scratch5[mm][0][0];
    float s = 0.f;
    #pragma unroll
    for (int j = 0; j < 16; ++j) s += sp[j * 64 + d];
    float sume = 0.f;
    #pragma unroll
    for (int j = 0; j < 16; ++j) sume += pe[mm][j];
    xagg_inter[mm][d] = s / sume;
  }
  __syncthreads();

  if (t < 512) {
    const int q2 = __builtin_amdgcn_readfirstlane(t >> 7);
    const int s2 = t & 127;
    const float* Wbase = pre + ((q2 < 2) ? P_WBL : P_WLBL) + (q2 & 1) * 512;
    const float* xrow = &xaggi[s2 * 68];
    float acc2[8];
    #pragma unroll
    for (int r = 0; r < 8; ++r) acc2[r] = 0.f;
    #pragma unroll
    for (int c = 0; c < 64; c += 4) {
      f32x4 xa = *(const f32x4*)(xrow + c);
      #pragma unroll
      for (int r = 0; r < 8; ++r)
        acc2[r] += xa.x * Wbase[r * 64 + c] + xa.y * Wbase[r * 64 + c + 1] +
                   xa.z * Wbase[r * 64 + c + 2] + xa.w * Wbase[r * 64 + c + 3];
    }
    const int bb = ((q2 < 2) ? P_BWB : P_BWL) + (q2 & 1) * 8;
    float* dst = ((q2 < 2) ? bigI : bigV) + (size_t)b * 2048 + s2 * 16 + (q2 & 1) * 8;
    f32x4 o0, o1;
    o0.x = acc2[0] + pre[bb + 0];
    o0.y = acc2[1] + pre[bb + 1];
    o0.z = acc2[2] + pre[bb + 2];
    o0.w = acc2[3] + pre[bb + 3];
    o1.x = acc2[4] + pre[bb + 4];
    o1.y = acc2[5] + pre[bb + 5];
    o1.z = acc2[6] + pre[bb + 6];
    o1.w = acc2[7] + pre[bb + 7];
    *(f32x4*)dst = o0;
    *(f32x4*)(dst + 4) = o1;
  } else if (t < 672) {
    int tt = t - 512;
    int o2 = tt & 31, mm = tt >> 5;
    const float* wr = pre + ((o2 < 16) ? (P_WAL + o2 * 64) : (P_WNAL + (o2 - 16) * 64));
    float p = 0.f;
    #pragma unroll
    for (int d = 0; d < 64; ++d) p += wr[d] * xagg_inter[mm][d];
    p += (o2 < 16) ? pre[P_BWA + o2] : pre[P_BWN + (o2 - 16)];
    float* os = p_small + (size_t)b * 160;
    if (o2 < 16) os[mm * 16 + o2] = p;
    else os[80 + mm * 16 + (o2 - 16)] = p;
  }
}

// ---------------------------------------------------------------- k1b: MFMA attention (256 threads, 4 waves)
__global__ __launch_bounds__(256, 2) void k1b(
    const float* __restrict__ xg_all, const float* __restrict__ Wc_g,
    const float* __restrict__ Wd_g, const float* __restrict__ p_small,
    const float* __restrict__ bigI, const float* __restrict__ bigV,
    unsigned int* __restrict__ feat16, float* __restrict__ bn_part) {
  __shared__ __align__(16) unsigned short slabI_[128 * 40];  // [s][k], k 0..15 data, 16..31 zero
  __shared__ __align__(16) unsigned short xlogB_[128 * 40];  // [n][k], same padding
  __shared__ __align__(16) unsigned short VT_[16 * 148];     // [p][s]
  __shared__ __align__(16) unsigned short Pm_[128 * 148];    // [n][s] bf16 exp values
  __shared__ __align__(16) float finL_[128 * 20];            // [n][p]
  __shared__ float s_sm[160];
  __shared__ float part1[2][32];
  __shared__ float part2[2][32];

  const int t = threadIdx.x;
  const int b = blockIdx.x;
  const int lane = t & 63;
  const int w = t >> 6;            // 4 waves; wave w owns n-tiles {2w, 2w+1}
  const int r = lane & 15;
  const int g = lane >> 4;

  // ---------------- stage ----------------
  // slabI: bigI f32 [s][16] -> bf16 [s][40] cols 0..15
  {
    const f32x4* gI = (const f32x4*)(bigI + (size_t)b * 2048);
    #pragma unroll
    for (int j = 0; j < 2; ++j) {
      int idx = t + 256 * j;             // 0..511
      int row = idx >> 2, c4 = idx & 3;
      f32x4 v = gI[idx];
      unsigned int* dst = (unsigned int*)&slabI_[row * 40 + c4 * 4];
      dst[0] = pack2bf(v.x, v.y);
      dst[1] = pack2bf(v.z, v.w);
    }
  }
  // zero pads (cols 16..31 of slabI and xlogB), u32 view pitch 20
  for (int i = t; i < 1024; i += 256) {
    int row = i >> 3, c = i & 7;
    ((unsigned int*)slabI_)[row * 20 + 8 + c] = 0u;
    ((unsigned int*)xlogB_)[row * 20 + 8 + c] = 0u;
  }
  // VT: bigV f32 [s][16] -> bf16 [p][148]
  {
    const f32x4* gV = (const f32x4*)(bigV + (size_t)b * 2048);
    int s = t >> 1, ph = (t & 1) * 8;
    f32x4 v0 = gV[t * 2];
    f32x4 v1 = gV[t * 2 + 1];
    VT_[(ph + 0) * 148 + s] = f2bf(v0.x);
    VT_[(ph + 1) * 148 + s] = f2bf(v0.y);
    VT_[(ph + 2) * 148 + s] = f2bf(v0.z);
    VT_[(ph + 3) * 148 + s] = f2bf(v0.w);
    VT_[(ph + 4) * 148 + s] = f2bf(v1.x);
    VT_[(ph + 5) * 148 + s] = f2bf(v1.y);
    VT_[(ph + 6) * 148 + s] = f2bf(v1.z);
    VT_[(ph + 7) * 148 + s] = f2bf(v1.w);
  }
  // xlog (t<128, thread = n): f32 dots, then bf16 into xlogB
  if (t < 128) {
    const int n = t;
    const f32x4* xgr = (const f32x4*)(xg_all + ((size_t)b * 128 + n) * 32);
    f32x4 xv[8];
    #pragma unroll
    for (int j = 0; j < 8; ++j) xv[j] = xgr[j];
    unsigned int px[8];
    #pragma unroll
    for (int o2 = 0; o2 < 8; ++o2) {
      float v0, v1;
      {
        const int o = o2 * 2;
        f32x4 s = (f32x4)0.f;
        #pragma unroll
        for (int j = 0; j < 8; ++j) s += xv[j] * *(const f32x4*)(Wc_g + o * 32 + 4 * j);
        v0 = s.x + s.y + s.z + s.w;
      }
      {
        const int o = o2 * 2 + 1;
        f32x4 s = (f32x4)0.f;
        #pragma unroll
        for (int j = 0; j < 8; ++j) s += xv[j] * *(const f32x4*)(Wc_g + o * 32 + 4 * j);
        v1 = s.x + s.y + s.z + s.w;
      }
      px[o2] = pack2bf(v0, v1);
    }
    unsigned int* dst = (unsigned int*)&xlogB_[n * 40];
    ((uint4*)dst)[0] = make_uint4(px[0], px[1], px[2], px[3]);
    ((uint4*)dst)[1] = make_uint4(px[4], px[5], px[6], px[7]);
  }
  if (t >= 96) {
    int i2 = t - 96;
    s_sm[i2] = p_small[(size_t)b * 160 + i2];
  }
  __syncthreads();  // bar1

  // ---------------- matmul1: logits + exp + P + row-sums ----------------
  float inv_rs[2][4];
  #pragma unroll
  for (int h = 0; h < 2; ++h) {
    const int nt = 2 * w + h;
    s16x8 afr = *(const s16x8*)&xlogB_[(nt * 16 + r) * 40 + g * 8];
    f32x4 d[8];
    #pragma unroll
    for (int st = 0; st < 8; ++st) {
      s16x8 bfr = *(const s16x8*)&slabI_[(st * 16 + r) * 40 + g * 8];
      d[st] = __builtin_amdgcn_mfma_f32_16x16x32_bf16(afr, bfr, (f32x4)0.f, 0, 0, 0);
    }
    float rs[4] = {0.f, 0.f, 0.f, 0.f};
    #pragma unroll
    for (int st = 0; st < 8; ++st) {
      #pragma unroll
      for (int j = 0; j < 4; ++j) {
        float e = __expf(d[st][j]);
        rs[j] += e;
        Pm_[(nt * 16 + g * 4 + j) * 148 + st * 16 + r] = f2bf(e);
      }
    }
    #pragma unroll
    for (int j = 0; j < 4; ++j) {
      rs[j] += __shfl_xor(rs[j], 1);
      rs[j] += __shfl_xor(rs[j], 2);
      rs[j] += __shfl_xor(rs[j], 4);
      rs[j] += __shfl_xor(rs[j], 8);
      inv_rs[h][j] = 1.f / rs[j];
    }
  }

  // ---------------- matmul2: fin = (P · V) * inv  (wave-private rows, no barrier)
  #pragma unroll
  for (int h = 0; h < 2; ++h) {
    const int nt = 2 * w + h;
    f32x4 c = (f32x4)0.f;
    const unsigned int* Pu = (const unsigned int*)Pm_;
    const unsigned int* Vu = (const unsigned int*)VT_;
    #pragma unroll
    for (int kt = 0; kt < 4; ++kt) {
      s16x8 afr, bfr;
      {
        int base = (nt * 16 + r) * 74 + kt * 16 + g * 4;
        uint2 a0 = *(const uint2*)&Pu[base];
        uint2 a1 = *(const uint2*)&Pu[base + 2];
        ((uint2*)&afr)[0] = a0;
        ((uint2*)&afr)[1] = a1;
      }
      {
        int base = r * 74 + kt * 16 + g * 4;
        uint2 b0 = *(const uint2*)&Vu[base];
        uint2 b1 = *(const uint2*)&Vu[base + 2];
        ((uint2*)&bfr)[0] = b0;
        ((uint2*)&bfr)[1] = b1;
      }
      c = __builtin_amdgcn_mfma_f32_16x16x32_bf16(afr, bfr, c, 0, 0, 0);
    }
    #pragma unroll
    for (int j = 0; j < 4; ++j)
      finL_[(nt * 16 + g * 4 + j) * 20 + r] = c[j] * inv_rs[h][j];
  }
  __syncthreads();  // bar2

  // ---------------- tail (t<128, thread = n): f_inter, feat, BN partials
  if (t < 128) {
    const int n = t;
    f32x4 fin[4];
    #pragma unroll
    for (int c = 0; c < 4; ++c) fin[c] = *(const f32x4*)&finL_[n * 20 + 4 * c];
    // xlog (bf16 re-read)
    f32x4 xme[4];
    {
      const unsigned int* src = (const unsigned int*)&xlogB_[n * 40];
      #pragma unroll
      for (int c = 0; c < 4; ++c) {
        unsigned int u0 = src[2 * c], u1 = src[2 * c + 1];
        f32x4 v;
        v.x = bflo(u0); v.y = bfhi(u0); v.z = bflo(u1); v.w = bfhi(u1);
        xme[c] = v;
      }
    }
    float L[5], mx3 = -1e30f;
    #pragma unroll
    for (int mm = 0; mm < 5; ++mm) {
      float p = 0.f;
      #pragma unroll
      for (int c = 0; c < 4; ++c) {
        #pragma unroll
        for (int jj = 0; jj < 4; ++jj) p += xme[c][jj] * s_sm[mm * 16 + 4 * c + jj];
      }
      L[mm] = p;
      mx3 = fmaxf(mx3, p);
    }
    float sum3 = 0.f;
    #pragma unroll
    for (int mm = 0; mm < 5; ++mm) { L[mm] = __expf(L[mm] - mx3); sum3 += L[mm]; }
    const float inv3 = 1.f / sum3;
    f32x4 fi[4];
    #pragma unroll
    for (int o4 = 0; o4 < 4; ++o4) {
      f32x4 rr;
      #pragma unroll
      for (int jj = 0; jj < 4; ++jj) {
        float p = 0.f;
        #pragma unroll
        for (int mm = 0; mm < 5; ++mm) p += L[mm] * s_sm[80 + mm * 16 + o4 * 4 + jj];
        rr[jj] = p * inv3;
      }
      fi[o4] = rr;
    }
    f32x4 feat[8];
    #pragma unroll
    for (int o4 = 0; o4 < 8; ++o4) {
      f32x4 rr;
      #pragma unroll
      for (int jj = 0; jj < 4; ++jj) {
        const int o = o4 * 4 + jj;
        f32x4 s = (f32x4)0.f;
        #pragma unroll
        for (int j = 0; j < 4; ++j) {
          s += fi[j]  * *(const f32x4*)(Wd_g + o * 32 + 4 * j);
          s += fin[j] * *(const f32x4*)(Wd_g + o * 32 + 16 + 4 * j);
        }
        rr[jj] = s.x + s.y + s.z + s.w;
      }
      feat[o4] = rr;
    }
    {
      unsigned int* op = feat16 + ((size_t)b * 128 + n) * 16;
      uint4 u0, u1, u2, u3;
      u0.x = pack2bf(feat[0].x, feat[0].y); u0.y = pack2bf(feat[0].z, feat[0].w);
      u0.z = pack2bf(feat[1].x, feat[1].y); u0.w = pack2bf(feat[1].z, feat[1].w);
      u1.x = pack2bf(feat[2].x, feat[2].y); u1.y = pack2bf(feat[2].z, feat[2].w);
      u1.z = pack2bf(feat[3].x, feat[3].y); u1.w = pack2bf(feat[3].z, feat[3].w);
      u2.x = pack2bf(feat[4].x, feat[4].y); u2.y = pack2bf(feat[4].z, feat[4].w);
      u2.z = pack2bf(feat[5].x, feat[5].y); u2.w = pack2bf(feat[5].z, feat[5].w);
      u3.x = pack2bf(feat[6].x, feat[6].y); u3.y = pack2bf(feat[6].z, feat[6].w);
      u3.z = pack2bf(feat[7].x, feat[7].y); u3.w = pack2bf(feat[7].z, feat[7].w);
      ((uint4*)op)[0] = u0;
      ((uint4*)op)[1] = u1;
      ((uint4*)op)[2] = u2;
      ((uint4*)op)[3] = u3;
    }
    const int w2 = t >> 6;
    const int kmap = ((lane & 1) << 4) | ((lane & 2) << 2) | (lane & 4) |
                     ((lane >> 2) & 2) | ((lane >> 4) & 1);
    {
      float a[32];
      #pragma unroll
      for (int o = 0; o < 32; ++o) a[o] = feat[o >> 2][o & 3];
      BSTAGE(1, 16) BSTAGE(2, 8) BSTAGE(4, 4) BSTAGE(8, 2) BSTAGE(16, 1)
      a[0] += __shfl_xor(a[0], 32);
      if (lane < 32) part1[w2][kmap] = a[0];
    }
    {
      float a[32];
      #pragma unroll
      for (int o = 0; o < 32; ++o) { float v = feat[o >> 2][o & 3]; a[o] = v * v; }
      BSTAGE(1, 16) BSTAGE(2, 8) BSTAGE(4, 4) BSTAGE(8, 2) BSTAGE(16, 1)
      a[0] += __shfl_xor(a[0], 32);
      if (lane < 32) part2[w2][kmap] = a[0];
    }
  }
  __syncthreads();  // bar3
  if (t < 64) {
    int c = t & 31, h = t >> 5;
    float v = h ? (part2[0][c] + part2[1][c]) : (part1[0][c] + part1[1][c]);
    bn_part[(size_t)b * 64 + h * 32 + c] = v;
  }
}

// ---------------------------------------------------------------- k2: BN coefficients (R12-verbatim)
__global__ __launch_bounds__(256, 1) void k2_stats(const float* __restrict__ bn_part,
                                                   const float* __restrict__ gamma,
                                                   const float* __restrict__ beta,
                                                   float* __restrict__ coef) {
  __shared__ float red[2][4];
  const int c = blockIdx.x;
  const int t = threadIdx.x;
  const int lane = t & 63, w = t >> 6;
  float s1 = 0.f, s2 = 0.f;
  for (int bb = t; bb < NB; bb += 256) {
    s1 += bn_part[(size_t)bb * 64 + c];
    s2 += bn_part[(size_t)bb * 64 + c + 32];
  }
  #pragma unroll
  for (int mask = 1; mask <= 32; mask <<= 1) {
    s1 += __shfl_xor(s1, mask);
    s2 += __shfl_xor(s2, mask);
  }
  if (lane == 0) { red[0][w] = s1; red[1][w] = s2; }
  __syncthreads();
  if (t == 0) {
    float S1 = red[0][0] + red[0][1] + red[0][2] + red[0][3];
    float S2 = red[1][0] + red[1][1] + red[1][2] + red[1][3];
    const float inv = 1.f / (float)(NB * 128);
    float mean = S1 * inv;
    float var = S2 * inv - mean * mean;
    float scl = gamma[c] * rsqrtf(var + 1e-5f);
    coef[c] = scl;
    coef[32 + c] = beta[c] - mean * scl;
  }
}

// ---------------------------------------------------------------- k3: BN apply + residual + leaky (R12-verbatim)
__global__ __launch_bounds__(256) void k3_final(const float* __restrict__ xg,
                                                const unsigned int* __restrict__ feat16,
                                                float* __restrict__ out,
                                                const float* __restrict__ coef) {
  __shared__ float s_c[64];
  if (threadIdx.x < 64) s_c[threadIdx.x] = coef[threadIdx.x];
  __syncthreads();
  size_t i4 = (size_t)blockIdx.x * 256 + threadIdx.x;
  uint2 fu = ((const uint2*)feat16)[i4];
  float4 x = ((const float4*)xg)[i4];
  int c = (int)((i4 * 4) & 31);
  float4 r;
  r.x = x.x + bflo(fu.x) * s_c[c + 0] + s_c[32 + c + 0];
  r.y = x.y + bfhi(fu.x) * s_c[c + 1] + s_c[32 + c + 1];
  r.z = x.z + bflo(fu.y) * s_c[c + 2] + s_c[32 + c + 2];
  r.w = x.w + bfhi(fu.y) * s_c[c + 3] + s_c[32 + c + 3];
  r.x = r.x >= 0.f ? r.x : 0.2f * r.x;
  r.y = r.y >= 0.f ? r.y : 0.2f * r.y;
  r.z = r.z >= 0.f ? r.z : 0.2f * r.z;
  r.w = r.w >= 0.f ? r.w : 0.2f * r.w;
  ((float4*)out)[i4] = r;
}

// ----------------------------------------------------------------
extern "C" void kernel_launch(void* const* d_in, const int* in_sizes, int n_in,
                              void* d_out, int out_size, void* d_ws, size_t ws_size,
                              hipStream_t stream) {
  const float* xg    = (const float*)d_in[0];
  const float* xl    = (const float*)d_in[1];
  const float* W_lin = (const float*)d_in[2];
  const float* b_lin = (const float*)d_in[3];
  const float* W_att = (const float*)d_in[4];
  const float* Wa    = (const float*)d_in[5];
  const float* Wb    = (const float*)d_in[6];
  const float* Wc    = (const float*)d_in[7];
  const float* Wn    = (const float*)d_in[8];
  const float* Wl    = (const float*)d_in[9];
  const float* Wd    = (const float*)d_in[10];
  const float* gamma = (const float*)d_in[11];
  const float* beta  = (const float*)d_in[12];
  float* out = (float*)d_out;
  float* ws = (float*)d_ws;
  float* pre = ws;
  float* bn_part = ws + WS_BNPART;
  float* coef = ws + WS_COEF;
  float* p_small = ws + WS_SMALL;
  float* bigI = ws + WS_BIG_I;
  float* bigV = ws + WS_BIG_V;
  unsigned int* feat16 = (unsigned int*)(ws + WS_FEAT16);

  hipLaunchKernelGGL(k0_pre, dim3(1), dim3(256), 0, stream,
                     W_lin, b_lin, W_att, Wa, Wb, Wn, Wl, pre);
  hipLaunchKernelGGL(k1a, dim3(NB), dim3(1024), 0, stream, xl, pre, p_small, bigI, bigV);
  hipLaunchKernelGGL(k1b, dim3(NB), dim3(256), 0, stream,
                     xg, Wc, Wd, p_small, bigI, bigV, feat16, bn_part);
  hipLaunchKernelGGL(k2_stats, dim3(32), dim3(256), 0, stream, bn_part, gamma, beta, coef);
  hipLaunchKernelGGL(k3_final, dim3(8192), dim3(256), 0, stream, xg, feat16, out, coef);
}

// Round 15
// 174.527 us; speedup vs baseline: 1.4099x; 1.0945x over previous
//
#include <hip/hip_runtime.h>
#include <math.h>

#define NB 2048
typedef float f32x4 __attribute__((ext_vector_type(4)));
typedef short s16x8 __attribute__((ext_vector_type(8)));

// pre[] float offsets (folded weights)
#define P_WAL 0
#define P_WBL 1024
#define P_WLBL 2048
#define P_WNAL 3072
#define P_WEFF 4096
#define P_BWA 4160
#define P_BWB 4176
#define P_BWL 4192
#define P_BWN 4208
#define P_C0  4224

// ws float offsets
#define WS_BNPART 4352
#define WS_COEF   135424
#define WS_SMALL  135488                  // [2048][160] f32
#define WS_BIG_I  463168                  // [2048][1024] uint (bf16 pairs, [s][16])
#define WS_BIG_V  (463168 + 2097152)      // [2048][1024] uint
#define WS_FEAT16 (463168 + 4194304)      // [2048][128][16] uint (bf16 pairs)

__device__ __forceinline__ unsigned short f2bf(float f) {
  unsigned int u = __float_as_uint(f);
  u += 0x7fffu + ((u >> 16) & 1u);
  return (unsigned short)(u >> 16);
}
__device__ __forceinline__ unsigned int pack2bf(float lo, float hi) {
  return (unsigned int)f2bf(lo) | ((unsigned int)f2bf(hi) << 16);
}
__device__ __forceinline__ float bflo(unsigned int u) { return __uint_as_float(u << 16); }
__device__ __forceinline__ float bfhi(unsigned int u) { return __uint_as_float(u & 0xffff0000u); }

#define BSTAGE(MASK, HALF)                                        \
  { const bool hi_ = (lane & (MASK)) != 0;                        \
    _Pragma("unroll")                                             \
    for (int k_ = 0; k_ < (HALF); ++k_) {                         \
      float mine_ = hi_ ? a[k_ + (HALF)] : a[k_];                 \
      float oth_  = hi_ ? a[k_] : a[k_ + (HALF)];                 \
      a[k_] = mine_ + __shfl_xor(oth_, (MASK));                   \
    } }

// ---------------------------------------------------------------- k0: fold weights (1024 threads, single pass per stage)
__global__ __launch_bounds__(1024) void k0_pre(const float* __restrict__ W_lin,
                                               const float* __restrict__ b_lin,
                                               const float* __restrict__ W_att,
                                               const float* __restrict__ Wa,
                                               const float* __restrict__ Wb,
                                               const float* __restrict__ Wn,
                                               const float* __restrict__ Wl,
                                               float* __restrict__ pre) {
  int t = threadIdx.x;
  {
    int o = t >> 6, d = t & 63;
    float sa = 0.f, sb = 0.f;
    for (int c = 0; c < 32; ++c) {
      float wl = W_lin[c * 64 + d];
      sa += Wa[o * 32 + c] * wl;
      sb += Wb[o * 32 + c] * wl;
    }
    pre[P_WAL + t] = sa;
    pre[P_WBL + t] = sb;
  }
  if (t < 64) {
    float s = 0.f;
    for (int c = 0; c < 32; ++c) s += W_att[c] * W_lin[c * 64 + t];
    pre[P_WEFF + t] = s;
  }
  if (t < 16) {
    float sa = 0.f, sb = 0.f;
    for (int c = 0; c < 32; ++c) {
      sa += Wa[t * 32 + c] * b_lin[c];
      sb += Wb[t * 32 + c] * b_lin[c];
    }
    pre[P_BWA + t] = sa;
    pre[P_BWB + t] = sb;
  }
  if (t == 0) {
    float s = 0.f;
    for (int c = 0; c < 32; ++c) s += W_att[c] * b_lin[c];
    pre[P_C0] = s;
  }
  __syncthreads();
  {
    int p_ = t >> 6, d = t & 63;
    float sl = 0.f, sn = 0.f;
    for (int o = 0; o < 16; ++o) {
      sl += Wl[p_ * 16 + o] * pre[P_WBL + o * 64 + d];
      sn += Wn[p_ * 16 + o] * pre[P_WAL + o * 64 + d];
    }
    pre[P_WLBL + t] = sl;
    pre[P_WNAL + t] = sn;
  }
  if (t < 16) {
    float sl = 0.f, sn = 0.f;
    for (int o = 0; o < 16; ++o) {
      sl += Wl[t * 16 + o] * pre[P_BWB + o];
      sn += Wn[t * 16 + o] * pre[P_BWA + o];
    }
    pre[P_BWL + t] = sl;
    pre[P_BWN + t] = sn;
  }
}

// ---------------------------------------------------------------- k1a: R10-proven body; phase-2 emits bf16
__global__ __launch_bounds__(1024, 2) void k1a(
    const float* __restrict__ xl_all, const float* __restrict__ pre,
    float* __restrict__ p_small, unsigned int* __restrict__ bigI,
    unsigned int* __restrict__ bigV) {
  __shared__ __align__(16) float xaggi[128 * 68];
  __shared__ f32x4 scratch5[5][16][16];
  __shared__ float pe[5][16];
  __shared__ float xagg_inter[5][64];

  const int t = threadIdx.x;
  const int b = blockIdx.x;
  const int lane = t & 63;
  const int w = t >> 6;
  const int q = lane >> 4;
  const int i16 = lane & 15;

  const float* xl = xl_all + (size_t)b * (5 * 128 * 64);
  const f32x4 weff4 = ((const f32x4*)(pre + P_WEFF))[i16];
  const float c0 = pre[P_C0];

  const float* xb = xl + (size_t)(8 * w + q) * 64 + 4 * i16;

  f32x4 xA[2], xB[2], acc[2];
  float Zk[2];
  #pragma unroll
  for (int k = 0; k < 2; ++k) {
    acc[k] = (f32x4)0.f;
    Zk[k] = 0.f;
    xA[k] = *(const f32x4*)(xb + k * 256);
  }

  #pragma unroll
  for (int m = 0; m < 5; ++m) {
    f32x4* xc = (m & 1) ? xB : xA;
    f32x4* xn = (m & 1) ? xA : xB;
    if (m < 4) {
      const float* np = xb + (size_t)(m + 1) * 8192;
      #pragma unroll
      for (int k = 0; k < 2; ++k) xn[k] = *(const f32x4*)(np + k * 256);
    }
    float a0, a1;
    {
      f32x4 p0 = xc[0] * weff4, p1 = xc[1] * weff4;
      a0 = p0.x + p0.y + p0.z + p0.w;
      a1 = p1.x + p1.y + p1.z + p1.w;
    }
    #pragma unroll
    for (int mask = 1; mask <= 8; mask <<= 1) {
      a0 += __shfl_xor(a0, mask);
      a1 += __shfl_xor(a1, mask);
    }
    float e0 = __expf(a0 + c0), e1 = __expf(a1 + c0);
    Zk[0] += e0; Zk[1] += e1;
    f32x4 pim;
    {
      f32x4 pr0 = e0 * xc[0];
      f32x4 pr1 = e1 * xc[1];
      acc[0] += pr0; acc[1] += pr1;
      pim = pr0 + pr1;
    }
    float se = e0 + e1;
    #pragma unroll
    for (int mask = 16; mask <= 32; mask <<= 1) {
      pim.x += __shfl_xor(pim.x, mask);
      pim.y += __shfl_xor(pim.y, mask);
      pim.z += __shfl_xor(pim.z, mask);
      pim.w += __shfl_xor(pim.w, mask);
      se += __shfl_xor(se, mask);
    }
    if (lane < 16) {
      scratch5[m][w][i16] = pim;
      if (i16 == 0) pe[m][w] = se;
    }
  }

  #pragma unroll
  for (int k = 0; k < 2; ++k) {
    float invz = 1.f / Zk[k];
    f32x4 v = acc[k] * invz;
    int r = 8 * w + 4 * k + q;
    *(f32x4*)&xaggi[r * 68 + 4 * i16] = v;
  }
  __syncthreads();

  if (t < 320) {
    int mm = t >> 6, d = t & 63;
    const float* sp = (const float*)&scratch5[mm][0][0];
    float s = 0.f;
    #pragma unroll
    for (int j = 0; j < 16; ++j) s += sp[j * 64 + d];
    float sume = 0.f;
    #pragma unroll
    for (int j = 0; j < 16; ++j) sume += pe[mm][j];
    xagg_inter[mm][d] = s / sume;
  }
  __syncthreads();

  if (t < 512) {
    const int q2 = __builtin_amdgcn_readfirstlane(t >> 7);
    const int s2 = t & 127;
    const float* Wbase = pre + ((q2 < 2) ? P_WBL : P_WLBL) + (q2 & 1) * 512;
    const float* xrow = &xaggi[s2 * 68];
    float acc2[8];
    #pragma unroll
    for (int r = 0; r < 8; ++r) acc2[r] = 0.f;
    #pragma unroll
    for (int c = 0; c < 64; c += 4) {
      f32x4 xa = *(const f32x4*)(xrow + c);
      #pragma unroll
      for (int r = 0; r < 8; ++r)
        acc2[r] += xa.x * Wbase[r * 64 + c] + xa.y * Wbase[r * 64 + c + 1] +
                   xa.z * Wbase[r * 64 + c + 2] + xa.w * Wbase[r * 64 + c + 3];
    }
    const int bb = ((q2 < 2) ? P_BWB : P_BWL) + (q2 & 1) * 8;
    unsigned int* dstu = ((q2 < 2) ? bigI : bigV) + (size_t)b * 1024 + s2 * 8 + (q2 & 1) * 4;
    uint4 o;
    o.x = pack2bf(acc2[0] + pre[bb + 0], acc2[1] + pre[bb + 1]);
    o.y = pack2bf(acc2[2] + pre[bb + 2], acc2[3] + pre[bb + 3]);
    o.z = pack2bf(acc2[4] + pre[bb + 4], acc2[5] + pre[bb + 5]);
    o.w = pack2bf(acc2[6] + pre[bb + 6], acc2[7] + pre[bb + 7]);
    *(uint4*)dstu = o;
  } else if (t < 672) {
    int tt = t - 512;
    int o2 = tt & 31, mm = tt >> 5;
    const float* wr = pre + ((o2 < 16) ? (P_WAL + o2 * 64) : (P_WNAL + (o2 - 16) * 64));
    float p = 0.f;
    #pragma unroll
    for (int d = 0; d < 64; ++d) p += wr[d] * xagg_inter[mm][d];
    p += (o2 < 16) ? pre[P_BWA + o2] : pre[P_BWN + (o2 - 16)];
    float* os = p_small + (size_t)b * 160;
    if (o2 < 16) os[mm * 16 + o2] = p;
    else os[80 + mm * 16 + (o2 - 16)] = p;
  }
}

// ---------------------------------------------------------------- k1b: MFMA attention (256 threads), bf16 I/V inputs
__global__ __launch_bounds__(256, 2) void k1b(
    const float* __restrict__ xg_all, const float* __restrict__ Wc_g,
    const float* __restrict__ Wd_g, const float* __restrict__ p_small,
    const unsigned int* __restrict__ bigI, const unsigned int* __restrict__ bigV,
    unsigned int* __restrict__ feat16, float* __restrict__ bn_part) {
  __shared__ __align__(16) unsigned short slabI_[128 * 40];  // [s][k], k 0..15 data, 16..31 zero
  __shared__ __align__(16) unsigned short xlogB_[128 * 40];  // [n][k], same padding
  __shared__ __align__(16) unsigned short VT_[16 * 148];     // [p][s]
  __shared__ __align__(16) unsigned short Pm_[128 * 148];    // [n][s] bf16 exp values
  __shared__ __align__(16) float finL_[128 * 20];            // [n][p]
  __shared__ float s_sm[160];
  __shared__ float part1[2][32];
  __shared__ float part2[2][32];

  const int t = threadIdx.x;
  const int b = blockIdx.x;
  const int lane = t & 63;
  const int w = t >> 6;            // 4 waves; wave w owns n-tiles {2w, 2w+1}
  const int r = lane & 15;
  const int g = lane >> 4;

  // ---------------- stage ----------------
  // slabI: bf16 [s][8 uints] -> LDS [s][40] cols 0..15 (1 uint4 per thread)
  {
    const uint4* gI = (const uint4*)(bigI + (size_t)b * 1024);
    int row = t >> 1, half = t & 1;
    uint4 v = gI[t];
    *(uint4*)((unsigned int*)slabI_ + row * 20 + half * 4) = v;
  }
  // zero pads (cols 16..31 of slabI and xlogB), u32 view pitch 20
  for (int i = t; i < 1024; i += 256) {
    int row = i >> 3, c = i & 7;
    ((unsigned int*)slabI_)[row * 20 + 8 + c] = 0u;
    ((unsigned int*)xlogB_)[row * 20 + 8 + c] = 0u;
  }
  // VT: bf16 [s][16] -> LDS transposed [p][148]
  {
    const uint4* gV = (const uint4*)(bigV + (size_t)b * 1024);
    int s = t >> 1, ph = (t & 1) * 8;
    uint4 u = gV[t];
    VT_[(ph + 0) * 148 + s] = (unsigned short)(u.x & 0xffffu);
    VT_[(ph + 1) * 148 + s] = (unsigned short)(u.x >> 16);
    VT_[(ph + 2) * 148 + s] = (unsigned short)(u.y & 0xffffu);
    VT_[(ph + 3) * 148 + s] = (unsigned short)(u.y >> 16);
    VT_[(ph + 4) * 148 + s] = (unsigned short)(u.z & 0xffffu);
    VT_[(ph + 5) * 148 + s] = (unsigned short)(u.z >> 16);
    VT_[(ph + 6) * 148 + s] = (unsigned short)(u.w & 0xffffu);
    VT_[(ph + 7) * 148 + s] = (unsigned short)(u.w >> 16);
  }
  // xlog (t<128, thread = n): f32 dots, then bf16 into xlogB
  if (t < 128) {
    const int n = t;
    const f32x4* xgr = (const f32x4*)(xg_all + ((size_t)b * 128 + n) * 32);
    f32x4 xv[8];
    #pragma unroll
    for (int j = 0; j < 8; ++j) xv[j] = xgr[j];
    unsigned int px[8];
    #pragma unroll
    for (int o2 = 0; o2 < 8; ++o2) {
      float v0, v1;
      {
        const int o = o2 * 2;
        f32x4 s = (f32x4)0.f;
        #pragma unroll
        for (int j = 0; j < 8; ++j) s += xv[j] * *(const f32x4*)(Wc_g + o * 32 + 4 * j);
        v0 = s.x + s.y + s.z + s.w;
      }
      {
        const int o = o2 * 2 + 1;
        f32x4 s = (f32x4)0.f;
        #pragma unroll
        for (int j = 0; j < 8; ++j) s += xv[j] * *(const f32x4*)(Wc_g + o * 32 + 4 * j);
        v1 = s.x + s.y + s.z + s.w;
      }
      px[o2] = pack2bf(v0, v1);
    }
    unsigned int* dst = (unsigned int*)&xlogB_[n * 40];
    ((uint4*)dst)[0] = make_uint4(px[0], px[1], px[2], px[3]);
    ((uint4*)dst)[1] = make_uint4(px[4], px[5], px[6], px[7]);
  }
  if (t >= 96) {
    int i2 = t - 96;
    s_sm[i2] = p_small[(size_t)b * 160 + i2];
  }
  __syncthreads();  // bar1

  // ---------------- matmul1: logits + exp + P + row-sums ----------------
  float inv_rs[2][4];
  #pragma unroll
  for (int h = 0; h < 2; ++h) {
    const int nt = 2 * w + h;
    s16x8 afr = *(const s16x8*)&xlogB_[(nt * 16 + r) * 40 + g * 8];
    f32x4 d[8];
    #pragma unroll
    for (int st = 0; st < 8; ++st) {
      s16x8 bfr = *(const s16x8*)&slabI_[(st * 16 + r) * 40 + g * 8];
      d[st] = __builtin_amdgcn_mfma_f32_16x16x32_bf16(afr, bfr, (f32x4)0.f, 0, 0, 0);
    }
    float rs[4] = {0.f, 0.f, 0.f, 0.f};
    #pragma unroll
    for (int st = 0; st < 8; ++st) {
      #pragma unroll
      for (int j = 0; j < 4; ++j) {
        float e = __expf(d[st][j]);
        rs[j] += e;
        Pm_[(nt * 16 + g * 4 + j) * 148 + st * 16 + r] = f2bf(e);
      }
    }
    #pragma unroll
    for (int j = 0; j < 4; ++j) {
      rs[j] += __shfl_xor(rs[j], 1);
      rs[j] += __shfl_xor(rs[j], 2);
      rs[j] += __shfl_xor(rs[j], 4);
      rs[j] += __shfl_xor(rs[j], 8);
      inv_rs[h][j] = 1.f / rs[j];
    }
  }

  // ---------------- matmul2: fin = (P · V) * inv
  #pragma unroll
  for (int h = 0; h < 2; ++h) {
    const int nt = 2 * w + h;
    f32x4 c = (f32x4)0.f;
    const unsigned int* Pu = (const unsigned int*)Pm_;
    const unsigned int* Vu = (const unsigned int*)VT_;
    #pragma unroll
    for (int kt = 0; kt < 4; ++kt) {
      s16x8 afr, bfr;
      {
        int base = (nt * 16 + r) * 74 + kt * 16 + g * 4;
        uint2 a0 = *(const uint2*)&Pu[base];
        uint2 a1 = *(const uint2*)&Pu[base + 2];
        ((uint2*)&afr)[0] = a0;
        ((uint2*)&afr)[1] = a1;
      }
      {
        int base = r * 74 + kt * 16 + g * 4;
        uint2 b0 = *(const uint2*)&Vu[base];
        uint2 b1 = *(const uint2*)&Vu[base + 2];
        ((uint2*)&bfr)[0] = b0;
        ((uint2*)&bfr)[1] = b1;
      }
      c = __builtin_amdgcn_mfma_f32_16x16x32_bf16(afr, bfr, c, 0, 0, 0);
    }
    #pragma unroll
    for (int j = 0; j < 4; ++j)
      finL_[(nt * 16 + g * 4 + j) * 20 + r] = c[j] * inv_rs[h][j];
  }
  __syncthreads();  // bar2

  // ---------------- tail (t<128, thread = n): f_inter, feat, BN partials
  if (t < 128) {
    const int n = t;
    f32x4 fin[4];
    #pragma unroll
    for (int c = 0; c < 4; ++c) fin[c] = *(const f32x4*)&finL_[n * 20 + 4 * c];
    f32x4 xme[4];
    {
      const unsigned int* src = (const unsigned int*)&xlogB_[n * 40];
      #pragma unroll
      for (int c = 0; c < 4; ++c) {
        unsigned int u0 = src[2 * c], u1 = src[2 * c + 1];
        f32x4 v;
        v.x = bflo(u0); v.y = bfhi(u0); v.z = bflo(u1); v.w = bfhi(u1);
        xme[c] = v;
      }
    }
    float L[5], mx3 = -1e30f;
    #pragma unroll
    for (int mm = 0; mm < 5; ++mm) {
      float p = 0.f;
      #pragma unroll
      for (int c = 0; c < 4; ++c) {
        #pragma unroll
        for (int jj = 0; jj < 4; ++jj) p += xme[c][jj] * s_sm[mm * 16 + 4 * c + jj];
      }
      L[mm] = p;
      mx3 = fmaxf(mx3, p);
    }
    float sum3 = 0.f;
    #pragma unroll
    for (int mm = 0; mm < 5; ++mm) { L[mm] = __expf(L[mm] - mx3); sum3 += L[mm]; }
    const float inv3 = 1.f / sum3;
    f32x4 fi[4];
    #pragma unroll
    for (int o4 = 0; o4 < 4; ++o4) {
      f32x4 rr;
      #pragma unroll
      for (int jj = 0; jj < 4; ++jj) {
        float p = 0.f;
        #pragma unroll
        for (int mm = 0; mm < 5; ++mm) p += L[mm] * s_sm[80 + mm * 16 + o4 * 4 + jj];
        rr[jj] = p * inv3;
      }
      fi[o4] = rr;
    }
    f32x4 feat[8];
    #pragma unroll
    for (int o4 = 0; o4 < 8; ++o4) {
      f32x4 rr;
      #pragma unroll
      for (int jj = 0; jj < 4; ++jj) {
        const int o = o4 * 4 + jj;
        f32x4 s = (f32x4)0.f;
        #pragma unroll
        for (int j = 0; j < 4; ++j) {
          s += fi[j]  * *(const f32x4*)(Wd_g + o * 32 + 4 * j);
          s += fin[j] * *(const f32x4*)(Wd_g + o * 32 + 16 + 4 * j);
        }
        rr[jj] = s.x + s.y + s.z + s.w;
      }
      feat[o4] = rr;
    }
    {
      unsigned int* op = feat16 + ((size_t)b * 128 + n) * 16;
      uint4 u0, u1, u2, u3;
      u0.x = pack2bf(feat[0].x, feat[0].y); u0.y = pack2bf(feat[0].z, feat[0].w);
      u0.z = pack2bf(feat[1].x, feat[1].y); u0.w = pack2bf(feat[1].z, feat[1].w);
      u1.x = pack2bf(feat[2].x, feat[2].y); u1.y = pack2bf(feat[2].z, feat[2].w);
      u1.z = pack2bf(feat[3].x, feat[3].y); u1.w = pack2bf(feat[3].z, feat[3].w);
      u2.x = pack2bf(feat[4].x, feat[4].y); u2.y = pack2bf(feat[4].z, feat[4].w);
      u2.z = pack2bf(feat[5].x, feat[5].y); u2.w = pack2bf(feat[5].z, feat[5].w);
      u3.x = pack2bf(feat[6].x, feat[6].y); u3.y = pack2bf(feat[6].z, feat[6].w);
      u3.z = pack2bf(feat[7].x, feat[7].y); u3.w = pack2bf(feat[7].z, feat[7].w);
      ((uint4*)op)[0] = u0;
      ((uint4*)op)[1] = u1;
      ((uint4*)op)[2] = u2;
      ((uint4*)op)[3] = u3;
    }
    const int w2 = t >> 6;
    const int kmap = ((lane & 1) << 4) | ((lane & 2) << 2) | (lane & 4) |
                     ((lane >> 2) & 2) | ((lane >> 4) & 1);
    {
      float a[32];
      #pragma unroll
      for (int o = 0; o < 32; ++o) a[o] = feat[o >> 2][o & 3];
      BSTAGE(1, 16) BSTAGE(2, 8) BSTAGE(4, 4) BSTAGE(8, 2) BSTAGE(16, 1)
      a[0] += __shfl_xor(a[0], 32);
      if (lane < 32) part1[w2][kmap] = a[0];
    }
    {
      float a[32];
      #pragma unroll
      for (int o = 0; o < 32; ++o) { float v = feat[o >> 2][o & 3]; a[o] = v * v; }
      BSTAGE(1, 16) BSTAGE(2, 8) BSTAGE(4, 4) BSTAGE(8, 2) BSTAGE(16, 1)
      a[0] += __shfl_xor(a[0], 32);
      if (lane < 32) part2[w2][kmap] = a[0];
    }
  }
  __syncthreads();  // bar3
  if (t < 64) {
    int c = t & 31, h = t >> 5;
    float v = h ? (part2[0][c] + part2[1][c]) : (part1[0][c] + part1[1][c]);
    bn_part[(size_t)b * 64 + h * 32 + c] = v;
  }
}

// ---------------------------------------------------------------- k2: BN coefficients (one block per channel)
__global__ __launch_bounds__(256, 1) void k2_stats(const float* __restrict__ bn_part,
                                                   const float* __restrict__ gamma,
                                                   const float* __restrict__ beta,
                                                   float* __restrict__ coef) {
  __shared__ float red[2][4];
  const int c = blockIdx.x;
  const int t = threadIdx.x;
  const int lane = t & 63, w = t >> 6;
  float s1 = 0.f, s2 = 0.f;
  for (int bb = t; bb < NB; bb += 256) {
    s1 += bn_part[(size_t)bb * 64 + c];
    s2 += bn_part[(size_t)bb * 64 + c + 32];
  }
  #pragma unroll
  for (int mask = 1; mask <= 32; mask <<= 1) {
    s1 += __shfl_xor(s1, mask);
    s2 += __shfl_xor(s2, mask);
  }
  if (lane == 0) { red[0][w] = s1; red[1][w] = s2; }
  __syncthreads();
  if (t == 0) {
    float S1 = red[0][0] + red[0][1] + red[0][2] + red[0][3];
    float S2 = red[1][0] + red[1][1] + red[1][2] + red[1][3];
    const float inv = 1.f / (float)(NB * 128);
    float mean = S1 * inv;
    float var = S2 * inv - mean * mean;
    float scl = gamma[c] * rsqrtf(var + 1e-5f);
    coef[c] = scl;
    coef[32 + c] = beta[c] - mean * scl;
  }
}

// ---------------------------------------------------------------- k3: BN apply + residual + leaky (bf16 feat -> f32 out)
__global__ __launch_bounds__(256) void k3_final(const float* __restrict__ xg,
                                                const unsigned int* __restrict__ feat16,
                                                float* __restrict__ out,
                                                const float* __restrict__ coef) {
  __shared__ float s_c[64];
  if (threadIdx.x < 64) s_c[threadIdx.x] = coef[threadIdx.x];
  __syncthreads();
  size_t i4 = (size_t)blockIdx.x * 256 + threadIdx.x;
  uint2 fu = ((const uint2*)feat16)[i4];
  float4 x = ((const float4*)xg)[i4];
  int c = (int)((i4 * 4) & 31);
  float4 r;
  r.x = x.x + bflo(fu.x) * s_c[c + 0] + s_c[32 + c + 0];
  r.y = x.y + bfhi(fu.x) * s_c[c + 1] + s_c[32 + c + 1];
  r.z = x.z + bflo(fu.y) * s_c[c + 2] + s_c[32 + c + 2];
  r.w = x.w + bfhi(fu.y) * s_c[c + 3] + s_c[32 + c + 3];
  r.x = r.x >= 0.f ? r.x : 0.2f * r.x;
  r.y = r.y >= 0.f ? r.y : 0.2f * r.y;
  r.z = r.z >= 0.f ? r.z : 0.2f * r.z;
  r.w = r.w >= 0.f ? r.w : 0.2f * r.w;
  ((float4*)out)[i4] = r;
}

// ----------------------------------------------------------------
extern "C" void kernel_launch(void* const* d_in, const int* in_sizes, int n_in,
                              void* d_out, int out_size, void* d_ws, size_t ws_size,
                              hipStream_t stream) {
  const float* xg    = (const float*)d_in[0];
  const float* xl    = (const float*)d_in[1];
  const float* W_lin = (const float*)d_in[2];
  const float* b_lin = (const float*)d_in[3];
  const float* W_att = (const float*)d_in[4];
  const float* Wa    = (const float*)d_in[5];
  const float* Wb    = (const float*)d_in[6];
  const float* Wc    = (const float*)d_in[7];
  const float* Wn    = (const float*)d_in[8];
  const float* Wl    = (const float*)d_in[9];
  const float* Wd    = (const float*)d_in[10];
  const float* gamma = (const float*)d_in[11];
  const float* beta  = (const float*)d_in[12];
  float* out = (float*)d_out;
  float* ws = (float*)d_ws;
  float* pre = ws;
  float* bn_part = ws + WS_BNPART;
  float* coef = ws + WS_COEF;
  float* p_small = ws + WS_SMALL;
  unsigned int* bigI = (unsigned int*)(ws + WS_BIG_I);
  unsigned int* bigV = (unsigned int*)(ws + WS_BIG_V);
  unsigned int* feat16 = (unsigned int*)(ws + WS_FEAT16);

  hipLaunchKernelGGL(k0_pre, dim3(1), dim3(1024), 0, stream,
                     W_lin, b_lin, W_att, Wa, Wb, Wn, Wl, pre);
  hipLaunchKernelGGL(k1a, dim3(NB), dim3(1024), 0, stream, xl, pre, p_small, bigI, bigV);
  hipLaunchKernelGGL(k1b, dim3(NB), dim3(256), 0, stream,
                     xg, Wc, Wd, p_small, bigI, bigV, feat16, bn_part);
  hipLaunchKernelGGL(k2_stats, dim3(32), dim3(256), 0, stream, bn_part, gamma, beta, coef);
  hipLaunchKernelGGL(k3_final, dim3(8192), dim3(256), 0, stream, xg, feat16, out, coef);
}